// Round 5
// baseline (1183.848 us; speedup 1.0000x reference)
//
#include <hip/hip_runtime.h>
#include <hip/hip_bf16.h>
#include <math.h>

#define N_NODES 20000
#define N_EDGES 160000
#define T_STEPS 8
#define F_INC   256
#define HEADS   4
#define CCH     128
#define KC      512   // HEADS*CCH
#define GHD     128
#define G3      384
#define SLOPE   0.2f
#define SEG     (N_EDGES + N_NODES)   // edges + self loops per t

typedef unsigned short u16;
typedef __attribute__((ext_vector_type(8))) short bf16x8;
typedef __attribute__((ext_vector_type(4))) float f32x4;

__device__ __forceinline__ float leakyf(float x) { return x > 0.f ? x : SLOPE * x; }
__device__ __forceinline__ float b2f(u16 u) {
  union { unsigned int i; float f; } x; x.i = ((unsigned int)u) << 16; return x.f;
}
__device__ __forceinline__ u16 f2b(float f) {
  union { float f; unsigned int i; } u; u.f = f;
  unsigned int r = u.i + 0x7FFFu + ((u.i >> 16) & 1u);
  return (u16)(r >> 16);
}
__device__ __forceinline__ float sigf(float x) { return 1.f / (1.f + expf(-x)); }

// async global->LDS 16B (wave-uniform LDS base + lane*16; per-lane global src)
__device__ __forceinline__ void gload16(const void* g, void* l) {
  __builtin_amdgcn_global_load_lds(
      (const __attribute__((address_space(1))) unsigned int*)g,
      (__attribute__((address_space(3))) unsigned int*)l, 16, 0, 0);
}

// ---------------------------------------------------------------------------
// bf16 MFMA GEMM: C[M,Nt] = A[M,K] @ B^T (+bias). A (M,K) bf16, B (Nt,K) bf16.
// 256 thr / 4 waves, tile 128x128, BK=32, 16x16x32 MFMA, fp32 accum.
// global_load_lds staging with XOR slot-swizzle folded into the per-lane
// GLOBAL source address (LDS dest linear). swz=1: bijective XCD-chunked
// block swizzle. FUSE=1 (xw gemm): fused a_src/a_dst row-dots.
// ---------------------------------------------------------------------------
template <int OBF, int FUSE>
__global__ __launch_bounds__(256) void gemm_bf16(
    const u16* __restrict__ A, const u16* __restrict__ B,
    const float* __restrict__ bias, void* __restrict__ Cout,
    int M, int K, int Nt, int swz,
    const float* __restrict__ attS, const float* __restrict__ attD,
    float* __restrict__ asrc, float* __restrict__ adst)
{
  __shared__ u16 As[128][32];
  __shared__ u16 Bs[128][32];
  __shared__ float s_as[128], s_ad[128];
  const int tid  = threadIdx.x;
  const int wave = tid >> 6, lane = tid & 63;
  const int wr = (wave >> 1) * 64, wc = (wave & 1) * 64;
  int bx = blockIdx.x, by = blockIdx.y;
  if (swz) {
    const int gx = gridDim.x;
    const int nwg = gx * (int)gridDim.y;
    const int lin = by * gx + bx;
    const int q = nwg >> 3, r = nwg & 7;
    const int xcd = lin & 7, idx = lin >> 3;
    const int wg = (xcd < r ? xcd * (q + 1) : r * (q + 1) + (xcd - r) * q) + idx;
    bx = wg % gx; by = wg / gx;
  }
  const int bm = by * 128, bn = bx * 128;
  const int l15 = lane & 15, g = lane >> 4;

  if (FUSE && tid < 128) { s_as[tid] = 0.f; s_ad[tid] = 0.f; }

  const int sr = tid >> 2, sd = tid & 3;
  const int ss = sd ^ ((sr >> 1) & 3);
  const u16* aS0 = A + (size_t)min(bm + sr,      M - 1) * K + ss * 8;
  const u16* aS1 = A + (size_t)min(bm + 64 + sr, M - 1) * K + ss * 8;
  const u16* bS0 = B + (size_t)(bn + sr)      * K + ss * 8;
  const u16* bS1 = B + (size_t)(bn + 64 + sr) * K + ss * 8;
  u16* lA0 = &As[0][0] + (size_t)(tid & ~63) * 8;
  u16* lA1 = lA0 + 2048;
  u16* lB0 = &Bs[0][0] + (size_t)(tid & ~63) * 8;
  u16* lB1 = lB0 + 2048;

  f32x4 acc[4][4];
  #pragma unroll
  for (int m = 0; m < 4; ++m)
    #pragma unroll
    for (int n = 0; n < 4; ++n)
      #pragma unroll
      for (int j = 0; j < 4; ++j) acc[m][n][j] = 0.f;

  const int nK = K >> 5;
  for (int kt = 0; kt < nK; ++kt) {
    const int ko = kt * 32;
    gload16(aS0 + ko, lA0);
    gload16(aS1 + ko, lA1);
    gload16(bS0 + ko, lB0);
    gload16(bS1 + ko, lB1);
    __syncthreads();
    bf16x8 af[4], bfr[4];
    #pragma unroll
    for (int m = 0; m < 4; ++m) {
      int row = wr + m * 16 + l15;
      af[m] = *(const bf16x8*)&As[row][(g ^ ((row >> 1) & 3)) * 8];
      int rowb = wc + m * 16 + l15;
      bfr[m] = *(const bf16x8*)&Bs[rowb][(g ^ ((rowb >> 1) & 3)) * 8];
    }
    #pragma unroll
    for (int m = 0; m < 4; ++m)
      #pragma unroll
      for (int n = 0; n < 4; ++n)
        acc[m][n] = __builtin_amdgcn_mfma_f32_16x16x32_bf16(af[m], bfr[n], acc[m][n], 0, 0, 0);
    __syncthreads();
  }
  #pragma unroll
  for (int m = 0; m < 4; ++m) {
    int row0 = bm + wr + m * 16 + g * 4;
    #pragma unroll
    for (int n = 0; n < 4; ++n) {
      int col = bn + wc + n * 16 + l15;
      float bv = bias ? bias[col] : 0.f;
      #pragma unroll
      for (int j = 0; j < 4; ++j) {
        int row = row0 + j;
        if (row < M) {
          float v = acc[m][n][j] + bv;
          if (OBF) ((u16*)Cout)[(size_t)row * Nt + col] = f2b(v);
          else     ((float*)Cout)[(size_t)row * Nt + col] = v;
        }
      }
    }
  }
  if (FUSE) {
    float ps[4][4], pd[4][4];
    #pragma unroll
    for (int m = 0; m < 4; ++m)
      #pragma unroll
      for (int j = 0; j < 4; ++j) { ps[m][j] = 0.f; pd[m][j] = 0.f; }
    #pragma unroll
    for (int n = 0; n < 4; ++n) {
      int cl = wc + n * 16 + l15;
      float wsv = attS[bn + cl], wdv = attD[bn + cl];
      #pragma unroll
      for (int m = 0; m < 4; ++m)
        #pragma unroll
        for (int j = 0; j < 4; ++j) {
          ps[m][j] = fmaf(acc[m][n][j], wsv, ps[m][j]);
          pd[m][j] = fmaf(acc[m][n][j], wdv, pd[m][j]);
        }
    }
    #pragma unroll
    for (int m = 0; m < 4; ++m)
      #pragma unroll
      for (int j = 0; j < 4; ++j)
        #pragma unroll
        for (int msk = 8; msk >= 1; msk >>= 1) {
          ps[m][j] += __shfl_xor(ps[m][j], msk);
          pd[m][j] += __shfl_xor(pd[m][j], msk);
        }
    if (l15 == 0) {
      #pragma unroll
      for (int m = 0; m < 4; ++m)
        #pragma unroll
        for (int j = 0; j < 4; ++j) {
          atomicAdd(&s_as[wr + m * 16 + g * 4 + j], ps[m][j]);
          atomicAdd(&s_ad[wr + m * 16 + g * 4 + j], pd[m][j]);
        }
    }
    __syncthreads();
    if (tid < 128) {
      int row = bm + tid;
      if (row < M) {
        int h = bn >> 7;
        asrc[(size_t)row * 4 + h] = s_as[tid];
        adst[(size_t)row * 4 + h] = s_ad[tid];
      }
    }
  }
}

// ---------------------------------------------------------------------------
// fp32 -> bf16 convert, 8 elems/thread (n % 8 == 0)
// ---------------------------------------------------------------------------
__global__ void convert_f32_bf16(const float* __restrict__ src, u16* __restrict__ dst, int n) {
  int i = (blockIdx.x * 256 + threadIdx.x) * 8;
  if (i >= n) return;
  float4 v0 = *(const float4*)(src + i);
  float4 v1 = *(const float4*)(src + i + 4);
  bf16x8 o;
  o[0] = (short)f2b(v0.x); o[1] = (short)f2b(v0.y);
  o[2] = (short)f2b(v0.z); o[3] = (short)f2b(v0.w);
  o[4] = (short)f2b(v1.x); o[5] = (short)f2b(v1.y);
  o[6] = (short)f2b(v1.z); o[7] = (short)f2b(v1.w);
  *(bf16x8*)(dst + i) = o;
}

// merged small-weight converts: W_ih, W_hh, W_att_in, W_att_out (8 elems/thr)
__global__ void convert_weights(const float* __restrict__ w_ih, const float* __restrict__ w_hh,
                                const float* __restrict__ w_in, const float* __restrict__ w_out,
                                u16* __restrict__ wihb, u16* __restrict__ whhb,
                                u16* __restrict__ winb, u16* __restrict__ woutb)
{
  int i = blockIdx.x * 256 + threadIdx.x;   // 18432 threads
  const float* src; u16* dst; int base;
  if      (i < 6144)  { src = w_ih;  dst = wihb;  base = i; }
  else if (i < 12288) { src = w_hh;  dst = whhb;  base = i - 6144; }
  else if (i < 14336) { src = w_in;  dst = winb;  base = i - 12288; }
  else                { src = w_out; dst = woutb; base = i - 14336; }
  int o = base * 8;
  float4 v0 = *(const float4*)(src + o);
  float4 v1 = *(const float4*)(src + o + 4);
  bf16x8 ov;
  ov[0] = (short)f2b(v0.x); ov[1] = (short)f2b(v0.y);
  ov[2] = (short)f2b(v0.z); ov[3] = (short)f2b(v0.w);
  ov[4] = (short)f2b(v1.x); ov[5] = (short)f2b(v1.y);
  ov[6] = (short)f2b(v1.z); ov[7] = (short)f2b(v1.w);
  *(bf16x8*)(dst + o) = ov;
}

__global__ void conv_transpose_wgat(const float* __restrict__ src, u16* __restrict__ dst) {
  int idx = blockIdx.x * 256 + threadIdx.x;
  if (idx >= KC * F_INC) return;
  int n = idx >> 8, k = idx & 255;
  dst[(size_t)n * F_INC + k] = f2b(src[(size_t)k * KC + n]);
}

// ---------------------------------------------------------------------------
// Batched edge counting-sort (all T at once)
// ---------------------------------------------------------------------------
__global__ void count_kernel(const int* __restrict__ graph, int* __restrict__ counts) {
  int e = blockIdx.x * 256 + threadIdx.x;
  int t = blockIdx.y;
  if (e < N_EDGES) {
    int d = graph[(size_t)t * 2 * N_EDGES + N_EDGES + e];
    atomicAdd(&counts[t * N_NODES + d], 1);
  }
}

__global__ __launch_bounds__(1024) void scan_kernel(
    const int* __restrict__ counts, int* __restrict__ offs)
{
  const int t = blockIdx.x;
  const int tid = threadIdx.x, lane = tid & 63, w = tid >> 6;
  __shared__ int s_wt[16];
  int carry = 0;
  const int base_abs = t * SEG;
  for (int base = 0; base < N_NODES; base += 1024) {
    int i = base + tid;
    int v = (i < N_NODES) ? (counts[t * N_NODES + i] + 1) : 0;  // +1 self loop
    int x = v;
    #pragma unroll
    for (int d = 1; d < 64; d <<= 1) {
      int nvl = __shfl_up(x, d, 64);
      if (lane >= d) x += nvl;
    }
    if (lane == 63) s_wt[w] = x;
    __syncthreads();
    if (tid < 16) {
      int y = s_wt[tid];
      #pragma unroll
      for (int d = 1; d < 16; d <<= 1) {
        int nvl = __shfl_up(y, d, 64);
        if (tid >= d) y += nvl;
      }
      s_wt[tid] = y;
    }
    __syncthreads();
    int wbase = (w > 0) ? s_wt[w - 1] : 0;
    int total = s_wt[15];
    if (i < N_NODES) offs[t * (N_NODES + 1) + i] = base_abs + carry + wbase + x - v;
    carry += total;
    __syncthreads();
  }
  if (tid == 0) offs[t * (N_NODES + 1) + N_NODES] = base_abs + carry;
}

__global__ void scatter_kernel(const int* __restrict__ graph, const int* __restrict__ offs,
                               int* __restrict__ cursor, int* __restrict__ ssrc)
{
  int i = blockIdx.x * 256 + threadIdx.x;
  int t = blockIdx.y;
  if (i >= SEG) return;
  int s, d;
  if (i < N_EDGES) {
    s = graph[(size_t)t * 2 * N_EDGES + i];
    d = graph[(size_t)t * 2 * N_EDGES + N_EDGES + i];
  } else {
    s = d = i - N_EDGES;
  }
  int pos = offs[t * (N_NODES + 1) + d] + atomicAdd(&cursor[t * N_NODES + d], 1);
  ssrc[pos] = s;
}

// ---------------------------------------------------------------------------
// Batched aggregate: one wave per (t, node); lane owns 8 contiguous channels
// of head lane>>4. SINGLE-pass online softmax (rescale accumulator) + 4-deep
// prefetch of the xw row gather (breaks the serial latency chain).
// ---------------------------------------------------------------------------
__global__ __launch_bounds__(256) void aggregate_kernel(
    const u16* __restrict__ xw, const float* __restrict__ a_src,
    const float* __restrict__ a_dst, const float* __restrict__ b_gat,
    const int* __restrict__ offs, const int* __restrict__ ssrc,
    u16* __restrict__ yout)
{
  const int wv = threadIdx.x >> 6, lane = threadIdx.x & 63;
  const int nd = blockIdx.x * 4 + wv;
  const int t  = blockIdx.y;
  __shared__ float s_w[4][64][4];
  __shared__ int   s_s[4][64];
  const int ob = t * (N_NODES + 1) + nd;
  const int beg = offs[ob], end = offs[ob + 1];
  const size_t rowbase = (size_t)t * N_NODES;
  const float4 adv = *(const float4*)&a_dst[(rowbase + nd) * 4];
  const int hl = lane >> 4;

  float m0=-INFINITY, m1=-INFINITY, m2=-INFINITY, m3=-INFINITY;
  float s0=0.f, s1=0.f, s2=0.f, s3=0.f;
  float acc[8] = {0.f,0.f,0.f,0.f,0.f,0.f,0.f,0.f};

  for (int base = beg; base < end; base += 64) {
    int e = base + lane;
    float a0=-INFINITY, a1=-INFINITY, a2=-INFINITY, a3=-INFINITY;
    if (e < end) {
      int s = ssrc[e];
      s_s[wv][lane] = s;
      float4 av = *(const float4*)&a_src[(rowbase + s) * 4];
      a0 = leakyf(av.x + adv.x); a1 = leakyf(av.y + adv.y);
      a2 = leakyf(av.z + adv.z); a3 = leakyf(av.w + adv.w);
    }
    // chunk max per head
    float c0=a0, c1=a1, c2=a2, c3=a3;
    #pragma unroll
    for (int msk = 32; msk >= 1; msk >>= 1) {
      c0 = fmaxf(c0, __shfl_xor(c0, msk)); c1 = fmaxf(c1, __shfl_xor(c1, msk));
      c2 = fmaxf(c2, __shfl_xor(c2, msk)); c3 = fmaxf(c3, __shfl_xor(c3, msk));
    }
    float n0 = fmaxf(m0, c0), n1 = fmaxf(m1, c1), n2 = fmaxf(m2, c2), n3 = fmaxf(m3, c3);
    float sc0 = expf(m0 - n0), sc1 = expf(m1 - n1), sc2 = expf(m2 - n2), sc3 = expf(m3 - n3);
    // rescale my head's accumulator
    float sch = (hl == 0) ? sc0 : (hl == 1) ? sc1 : (hl == 2) ? sc2 : sc3;
    #pragma unroll
    for (int k = 0; k < 8; ++k) acc[k] *= sch;
    // weights for this chunk (computed ONCE)
    float w0 = expf(a0 - n0), w1 = expf(a1 - n1), w2 = expf(a2 - n2), w3 = expf(a3 - n3);
    s_w[wv][lane][0] = w0; s_w[wv][lane][1] = w1;
    s_w[wv][lane][2] = w2; s_w[wv][lane][3] = w3;
    // sum of weights per head
    float t0=w0, t1=w1, t2=w2, t3=w3;
    #pragma unroll
    for (int msk = 32; msk >= 1; msk >>= 1) {
      t0 += __shfl_xor(t0, msk); t1 += __shfl_xor(t1, msk);
      t2 += __shfl_xor(t2, msk); t3 += __shfl_xor(t3, msk);
    }
    s0 = s0 * sc0 + t0; s1 = s1 * sc1 + t1;
    s2 = s2 * sc2 + t2; s3 = s3 * sc3 + t3;
    m0 = n0; m1 = n1; m2 = n2; m3 = n3;

    // accumulate with 4-deep prefetch
    int cnt = min(64, end - base);
    int4 buf[4];
    #pragma unroll
    for (int j = 0; j < 4; ++j)
      if (j < cnt)
        buf[j] = *(const int4*)&xw[(rowbase + s_s[wv][j]) * KC + lane * 8];
    for (int e2 = 0; e2 < cnt; ++e2) {
      int4 xi = buf[e2 & 3];
      if (e2 + 4 < cnt)
        buf[e2 & 3] = *(const int4*)&xw[(rowbase + s_s[wv][e2 + 4]) * KC + lane * 8];
      float w = s_w[wv][e2][hl];
      acc[0] = fmaf(w, __uint_as_float((unsigned)xi.x << 16), acc[0]);
      acc[1] = fmaf(w, __uint_as_float((unsigned)xi.x & 0xffff0000u), acc[1]);
      acc[2] = fmaf(w, __uint_as_float((unsigned)xi.y << 16), acc[2]);
      acc[3] = fmaf(w, __uint_as_float((unsigned)xi.y & 0xffff0000u), acc[3]);
      acc[4] = fmaf(w, __uint_as_float((unsigned)xi.z << 16), acc[4]);
      acc[5] = fmaf(w, __uint_as_float((unsigned)xi.z & 0xffff0000u), acc[5]);
      acc[6] = fmaf(w, __uint_as_float((unsigned)xi.w << 16), acc[6]);
      acc[7] = fmaf(w, __uint_as_float((unsigned)xi.w & 0xffff0000u), acc[7]);
    }
  }
  // normalize by my head's sum, then mean over heads
  float sh = (hl == 0) ? s0 : (hl == 1) ? s1 : (hl == 2) ? s2 : s3;
  float inv = 1.f / (sh + 1e-16f);
  #pragma unroll
  for (int k = 0; k < 8; ++k) {
    acc[k] *= inv;
    acc[k] += __shfl_xor(acc[k], 16);
    acc[k] += __shfl_xor(acc[k], 32);
  }
  if (lane < 16) {
    bf16x8 ov;
    #pragma unroll
    for (int k = 0; k < 8; ++k) {
      float v = acc[k] * 0.25f + b_gat[lane * 8 + k];
      ov[k] = (short)f2b(leakyf(v));
    }
    *(bf16x8*)&yout[(rowbase + nd) * GHD + lane * 8] = ov;
  }
}

// ---------------------------------------------------------------------------
// GRU t=0 combine (h_prev = 0, gh = b_hh); writes ctx0 bf16 + hf fp32
// ---------------------------------------------------------------------------
__global__ void gru_combine0(const u16* __restrict__ gi_t, const float* __restrict__ b_hh,
                             u16* __restrict__ ctx0, float* __restrict__ hf)
{
  int idx = blockIdx.x * 256 + threadIdx.x;
  if (idx >= N_NODES * GHD) return;
  int n = idx >> 7, c = idx & 127;
  size_t gb = (size_t)n * G3;
  float ir = b2f(gi_t[gb + c]), iz = b2f(gi_t[gb + 128 + c]), in_ = b2f(gi_t[gb + 256 + c]);
  float r = sigf(ir + b_hh[c]);
  float z = sigf(iz + b_hh[128 + c]);
  float nn = tanhf(in_ + r * b_hh[256 + c]);
  float h = (1.f - z) * nn;
  ctx0[idx] = f2b(h);
  hf[idx] = h;
}

// ---------------------------------------------------------------------------
// Fused gh-GEMM (64x384 tile) + GRU combine. A = ctx[t-1] (bf16), carry hf
// fp32 in-place; writes ctx[t] bf16 + hf. global_load_lds staging.
// ---------------------------------------------------------------------------
__global__ __launch_bounds__(256) void gru_fused(
    const u16* __restrict__ hprev, const u16* __restrict__ Whh,
    const float* __restrict__ b_hh, const u16* __restrict__ gi_t,
    float* __restrict__ hf, u16* __restrict__ ctx_out)
{
  __shared__ u16 lds[64 * 384];                       // 48 KB, dual-purpose
  u16 (*As)[32] = (u16(*)[32])lds;                    // 64 x 32
  u16 (*Bs)[32] = (u16(*)[32])(lds + 64 * 32);        // 384 x 32
  const int tid = threadIdx.x, lane = tid & 63, wv = tid >> 6;
  const int l15 = lane & 15, g = lane >> 4;
  const int bm = blockIdx.x * 64;

  const int sr = tid >> 2, sd = tid & 3;
  const int ss = sd ^ ((sr >> 1) & 3);
  const u16* aS = hprev + (size_t)min(bm + sr, N_NODES - 1) * GHD + ss * 8;
  u16* lA = lds + (size_t)(tid & ~63) * 8;
  const u16* bS[6]; u16* lB[6];
  #pragma unroll
  for (int p = 0; p < 6; ++p) {
    int r = sr + p * 64;
    bS[p] = Whh + (size_t)r * GHD + ss * 8;
    lB[p] = lds + 64 * 32 + (size_t)(p * 256 + (tid & ~63)) * 8;
  }

  f32x4 acc[4][6];
  #pragma unroll
  for (int m = 0; m < 4; ++m)
    #pragma unroll
    for (int n = 0; n < 6; ++n)
      #pragma unroll
      for (int j = 0; j < 4; ++j) acc[m][n][j] = 0.f;

  #pragma unroll
  for (int kt = 0; kt < 4; ++kt) {
    const int ko = kt * 32;
    gload16(aS + ko, lA);
    #pragma unroll
    for (int p = 0; p < 6; ++p) gload16(bS[p] + ko, lB[p]);
    __syncthreads();
    bf16x8 af[4], bfr[6];
    #pragma unroll
    for (int m = 0; m < 4; ++m) {
      int row = m * 16 + l15;
      af[m] = *(const bf16x8*)&As[row][(g ^ ((row >> 1) & 3)) * 8];
    }
    #pragma unroll
    for (int n = 0; n < 6; ++n) {
      int row = wv * 96 + n * 16 + l15;
      bfr[n] = *(const bf16x8*)&Bs[row][(g ^ ((row >> 1) & 3)) * 8];
    }
    #pragma unroll
    for (int m = 0; m < 4; ++m)
      #pragma unroll
      for (int n = 0; n < 6; ++n)
        acc[m][n] = __builtin_amdgcn_mfma_f32_16x16x32_bf16(af[m], bfr[n], acc[m][n], 0, 0, 0);
    __syncthreads();
  }
  #pragma unroll
  for (int m = 0; m < 4; ++m)
    #pragma unroll
    for (int n = 0; n < 6; ++n) {
      int c = wv * 96 + n * 16 + l15;
      float bb = b_hh[c];
      #pragma unroll
      for (int j = 0; j < 4; ++j) {
        int r = m * 16 + g * 4 + j;
        lds[r * 384 + (((c >> 3) ^ (r & 7)) << 3) + (c & 7)] = f2b(acc[m][n][j] + bb);
      }
    }
  __syncthreads();
  {
    int r = tid >> 2, gr = bm + r;
    if (gr < N_NODES) {
      const int cg = (tid & 3) * 32;
      const size_t gb = (size_t)gr * G3;
      const size_t cb = (size_t)gr * GHD;
      #pragma unroll
      for (int q = 0; q < 4; ++q) {
        int c0 = cg + q * 8;
        int sl0 = ((c0 >> 3) ^ (r & 7));
        int sl1 = (((128 + c0) >> 3) ^ (r & 7));
        int sl2 = (((256 + c0) >> 3) ^ (r & 7));
        bf16x8 hr8 = *(bf16x8*)&lds[r * 384 + sl0 * 8];
        bf16x8 hz8 = *(bf16x8*)&lds[r * 384 + sl1 * 8];
        bf16x8 hn8 = *(bf16x8*)&lds[r * 384 + sl2 * 8];
        bf16x8 ir8 = *(const bf16x8*)&gi_t[gb + c0];
        bf16x8 iz8 = *(const bf16x8*)&gi_t[gb + 128 + c0];
        bf16x8 in8 = *(const bf16x8*)&gi_t[gb + 256 + c0];
        float4 hp0 = *(const float4*)&hf[cb + c0];
        float4 hp1 = *(const float4*)&hf[cb + c0 + 4];
        float hp[8] = {hp0.x, hp0.y, hp0.z, hp0.w, hp1.x, hp1.y, hp1.z, hp1.w};
        float cv[8];
        bf16x8 hv;
        #pragma unroll
        for (int k = 0; k < 8; ++k) {
          float rr = sigf(b2f((u16)ir8[k]) + b2f((u16)hr8[k]));
          float zz = sigf(b2f((u16)iz8[k]) + b2f((u16)hz8[k]));
          float nn = tanhf(b2f((u16)in8[k]) + rr * b2f((u16)hn8[k]));
          float h = (1.f - zz) * nn + zz * hp[k];
          cv[k] = h;
          hv[k] = (short)f2b(h);
        }
        *(float4*)&hf[cb + c0]     = make_float4(cv[0], cv[1], cv[2], cv[3]);
        *(float4*)&hf[cb + c0 + 4] = make_float4(cv[4], cv[5], cv[6], cv[7]);
        *(bf16x8*)&ctx_out[cb + c0] = hv;
      }
    }
  }
}

// ---------------------------------------------------------------------------
// Temporal attention middle: scores + softmax + mix. One wave / node.
// ---------------------------------------------------------------------------
__global__ __launch_bounds__(256) void attn_mid(
    const u16* __restrict__ ctx, const float* __restrict__ q,
    u16* __restrict__ comb)
{
  const int node = blockIdx.x * 4 + (threadIdx.x >> 6);
  const int lane = threadIdx.x & 63;
  if (node >= N_NODES) return;
  const float q0 = q[(size_t)node * GHD + lane];
  const float q1 = q[(size_t)node * GHD + 64 + lane];
  float c0[T_STEPS], c1[T_STEPS], w[T_STEPS];
  float mx = -1e30f;
  #pragma unroll
  for (int t = 0; t < T_STEPS; ++t) {
    const u16* cr = ctx + ((size_t)t * N_NODES + node) * GHD;
    c0[t] = b2f(cr[lane]); c1[t] = b2f(cr[64 + lane]);
    float p = q0 * c0[t] + q1 * c1[t];
    #pragma unroll
    for (int m = 32; m >= 1; m >>= 1) p += __shfl_xor(p, m);
    w[t] = p;
    mx = fmaxf(mx, p);
  }
  float s = 0.f;
  #pragma unroll
  for (int t = 0; t < T_STEPS; ++t) { w[t] = expf(w[t] - mx); s += w[t]; }
  const float inv = 1.f / s;
  float m0 = 0.f, m1 = 0.f;
  #pragma unroll
  for (int t = 0; t < T_STEPS; ++t) { m0 = fmaf(w[t], c0[t], m0); m1 = fmaf(w[t], c1[t], m1); }
  m0 *= inv; m1 *= inv;
  u16* cb = comb + (size_t)node * 2 * GHD;
  cb[lane]       = f2b(m0);
  cb[64 + lane]  = f2b(m1);
  cb[128 + lane] = f2b(q0);
  cb[192 + lane] = f2b(q1);
}

// ---------------------------------------------------------------------------
// tanh + leaky + classifier + log_softmax. One wave / node.
// ---------------------------------------------------------------------------
__global__ __launch_bounds__(256) void logits_kernel(
    const u16* __restrict__ ao, const float* __restrict__ W_cls,
    const float* __restrict__ b_cls, float* __restrict__ out)
{
  const int node = blockIdx.x * 4 + (threadIdx.x >> 6);
  const int lane = threadIdx.x & 63;
  if (node >= N_NODES) return;
  float o0 = leakyf(tanhf(b2f(ao[(size_t)node * GHD + lane])));
  float o1 = leakyf(tanhf(b2f(ao[(size_t)node * GHD + 64 + lane])));
  float p0 = o0 * W_cls[lane] + o1 * W_cls[64 + lane];
  float p1 = o0 * W_cls[128 + lane] + o1 * W_cls[192 + lane];
  #pragma unroll
  for (int m = 32; m >= 1; m >>= 1) { p0 += __shfl_xor(p0, m); p1 += __shfl_xor(p1, m); }
  if (lane == 0) {
    float l0 = p0 + b_cls[0];
    float l1 = p1 + b_cls[1];
    float mx = fmaxf(l0, l1);
    float lse = mx + logf(expf(l0 - mx) + expf(l1 - mx));
    out[(size_t)node * 2 + 0] = l0 - lse;
    out[(size_t)node * 2 + 1] = l1 - lse;
  }
}

// ---------------------------------------------------------------------------
extern "C" void kernel_launch(void* const* d_in, const int* in_sizes, int n_in,
                              void* d_out, int out_size, void* d_ws, size_t ws_size,
                              hipStream_t stream)
{
  const int*   graph     = (const int*)  d_in[0];
  const float* fts       = (const float*)d_in[1];
  const float* W_gat     = (const float*)d_in[3];
  const float* att_src   = (const float*)d_in[4];
  const float* att_dst   = (const float*)d_in[5];
  const float* b_gat     = (const float*)d_in[6];
  const float* W_ih      = (const float*)d_in[7];
  const float* W_hh      = (const float*)d_in[8];
  const float* b_ih      = (const float*)d_in[9];
  const float* b_hh      = (const float*)d_in[10];
  const float* W_att_in  = (const float*)d_in[11];
  const float* W_att_out = (const float*)d_in[12];
  const float* W_cls     = (const float*)d_in[13];
  const float* b_cls     = (const float*)d_in[14];
  float* out = (float*)d_out;

  char* ws = (char*)d_ws;
  size_t off = 0;
  auto alloc = [&](size_t bytes) {
    void* p = ws + off;
    off = (off + bytes + 255) & ~(size_t)255;
    return p;
  };
  const size_t NT = (size_t)T_STEPS * N_NODES;      // 160000 rows
  u16*   wgatT = (u16*)alloc((size_t)KC * F_INC * 2);
  u16*   wihb  = (u16*)alloc((size_t)G3 * GHD * 2);
  u16*   whhb  = (u16*)alloc((size_t)G3 * GHD * 2);
  u16*   winb  = (u16*)alloc((size_t)GHD * GHD * 2);
  u16*   woutb = (u16*)alloc((size_t)GHD * 2 * GHD * 2);
  u16*   fbf   = (u16*)alloc(NT * F_INC * 2);       // 82 MB  fts bf16
  u16*   xw    = (u16*)alloc(NT * KC * 2);          // 164 MB
  float* asrc  = (float*)alloc(NT * 4 * 4);
  float* adst  = (float*)alloc(NT * 4 * 4);
  u16*   yall  = (u16*)alloc(NT * GHD * 2);         // 41 MB
  u16*   giall = (u16*)alloc(NT * G3 * 2);          // 123 MB
  u16*   ctx   = (u16*)alloc(NT * GHD * 2);         // 41 MB (bf16 h record)
  float* hf    = (float*)alloc((size_t)N_NODES * GHD * 4); // fp32 h carry
  float* qf    = (float*)alloc((size_t)N_NODES * GHD * 4);
  u16*   comb  = (u16*)alloc((size_t)N_NODES * 2 * GHD * 2);
  u16*   aob   = (u16*)alloc((size_t)N_NODES * GHD * 2);
  int* counts  = (int*)alloc((size_t)2 * T_STEPS * N_NODES * 4); // counts + cursor
  int* cursor  = counts + T_STEPS * N_NODES;
  int* offs    = (int*)alloc((size_t)T_STEPS * (N_NODES + 1) * 4);
  int* ssrc    = (int*)alloc((size_t)T_STEPS * SEG * 4);

  // weight converts
  conv_transpose_wgat<<<dim3((KC * F_INC + 255) / 256), 256, 0, stream>>>(W_gat, wgatT);
  convert_weights<<<dim3(72), 256, 0, stream>>>(W_ih, W_hh, W_att_in, W_att_out,
                                                wihb, whhb, winb, woutb);

  // batched edge sort
  hipMemsetAsync(counts, 0, (size_t)2 * T_STEPS * N_NODES * 4, stream);
  count_kernel<<<dim3(N_EDGES / 256, T_STEPS), 256, 0, stream>>>(graph, counts);
  scan_kernel<<<dim3(T_STEPS), 1024, 0, stream>>>(counts, offs);
  scatter_kernel<<<dim3((SEG + 255) / 256, T_STEPS), 256, 0, stream>>>(graph, offs, cursor, ssrc);

  // fts -> bf16 (one streaming pass)
  convert_f32_bf16<<<dim3((int)(NT * F_INC / 8 / 256)), 256, 0, stream>>>(
      fts, fbf, (int)(NT * F_INC));

  // xw = fbf @ W_gat^T for ALL t + fused a_src/a_dst
  gemm_bf16<1, 1><<<dim3(KC / 128, (int)(NT / 128)), 256, 0, stream>>>(
      fbf, wgatT, nullptr, xw, (int)NT, F_INC, KC, 1, att_src, att_dst, asrc, adst);

  // batched aggregate -> y for ALL t
  aggregate_kernel<<<dim3(N_NODES / 4, T_STEPS), 256, 0, stream>>>(
      xw, asrc, adst, b_gat, offs, ssrc, yall);

  // gi = y @ W_ih^T + b_ih for ALL t
  gemm_bf16<1, 0><<<dim3(G3 / 128, (int)(NT / 128)), 256, 0, stream>>>(
      yall, wihb, b_ih, giall, (int)NT, GHD, G3, 1, nullptr, nullptr, nullptr, nullptr);

  // GRU recurrence (ctx record bf16, carry fp32 in hf)
  gru_combine0<<<dim3(N_NODES * GHD / 256), 256, 0, stream>>>(giall, b_hh, ctx, hf);
  for (int t = 1; t < T_STEPS; ++t) {
    gru_fused<<<dim3((N_NODES + 63) / 64), 256, 0, stream>>>(
        ctx + (size_t)(t - 1) * N_NODES * GHD, whhb, b_hh,
        giall + (size_t)t * N_NODES * G3, hf,
        ctx + (size_t)t * N_NODES * GHD);
  }

  // temporal attention tail
  gemm_bf16<0, 0><<<dim3(1, (N_NODES + 127) / 128), 256, 0, stream>>>(
      ctx + (size_t)(T_STEPS - 1) * N_NODES * GHD, winb, nullptr, qf,
      N_NODES, GHD, GHD, 0, nullptr, nullptr, nullptr, nullptr);
  attn_mid<<<dim3(N_NODES / 4), 256, 0, stream>>>(ctx, qf, comb);
  gemm_bf16<1, 0><<<dim3(1, (N_NODES + 127) / 128), 256, 0, stream>>>(
      comb, woutb, nullptr, aob, N_NODES, 2 * GHD, GHD, 0, nullptr, nullptr, nullptr, nullptr);
  logits_kernel<<<dim3(N_NODES / 4), 256, 0, stream>>>(aob, W_cls, b_cls, out);
}

// Round 6
// 870.578 us; speedup vs baseline: 1.3598x; 1.3598x over previous
//
#include <hip/hip_runtime.h>
#include <hip/hip_bf16.h>
#include <math.h>

#define N_NODES 20000
#define N_EDGES 160000
#define T_STEPS 8
#define F_INC   256
#define HEADS   4
#define CCH     128
#define KC      512   // HEADS*CCH
#define GHD     128
#define G3      384
#define SLOPE   0.2f
#define SEG     (N_EDGES + N_NODES)   // edges + self loops per t

typedef unsigned short u16;
typedef __attribute__((ext_vector_type(8))) short bf16x8;
typedef __attribute__((ext_vector_type(4))) float f32x4;

__device__ __forceinline__ float leakyf(float x) { return x > 0.f ? x : SLOPE * x; }
__device__ __forceinline__ float b2f(u16 u) {
  union { unsigned int i; float f; } x; x.i = ((unsigned int)u) << 16; return x.f;
}
__device__ __forceinline__ u16 f2b(float f) {
  union { float f; unsigned int i; } u; u.f = f;
  unsigned int r = u.i + 0x7FFFu + ((u.i >> 16) & 1u);
  return (u16)(r >> 16);
}
__device__ __forceinline__ float sigf(float x) { return 1.f / (1.f + expf(-x)); }

// async global->LDS 16B (wave-uniform LDS base + lane*16; per-lane global src)
__device__ __forceinline__ void gload16(const void* g, void* l) {
  __builtin_amdgcn_global_load_lds(
      (const __attribute__((address_space(1))) unsigned int*)g,
      (__attribute__((address_space(3))) unsigned int*)l, 16, 0, 0);
}

// ---------------------------------------------------------------------------
// bf16 MFMA GEMM: C[M,Nt] = A[M,K] @ B^T (+bias). A (M,K) bf16, B (Nt,K) bf16.
// 256 thr / 4 waves, tile 128x128, BK=32, 16x16x32 MFMA, fp32 accum.
// global_load_lds staging, XOR slot-swizzle folded into per-lane GLOBAL src.
// swz=1: bijective XCD-chunked block swizzle. FUSE=1: fused a_src/a_dst dots.
// ---------------------------------------------------------------------------
template <int OBF, int FUSE>
__global__ __launch_bounds__(256) void gemm_bf16(
    const u16* __restrict__ A, const u16* __restrict__ B,
    const float* __restrict__ bias, void* __restrict__ Cout,
    int M, int K, int Nt, int swz,
    const float* __restrict__ attS, const float* __restrict__ attD,
    float* __restrict__ asrc, float* __restrict__ adst)
{
  __shared__ u16 As[128][32];
  __shared__ u16 Bs[128][32];
  __shared__ float s_as[128], s_ad[128];
  const int tid  = threadIdx.x;
  const int wave = tid >> 6, lane = tid & 63;
  const int wr = (wave >> 1) * 64, wc = (wave & 1) * 64;
  int bx = blockIdx.x, by = blockIdx.y;
  if (swz) {
    const int gx = gridDim.x;
    const int nwg = gx * (int)gridDim.y;
    const int lin = by * gx + bx;
    const int q = nwg >> 3, r = nwg & 7;
    const int xcd = lin & 7, idx = lin >> 3;
    const int wg = (xcd < r ? xcd * (q + 1) : r * (q + 1) + (xcd - r) * q) + idx;
    bx = wg % gx; by = wg / gx;
  }
  const int bm = by * 128, bn = bx * 128;
  const int l15 = lane & 15, g = lane >> 4;

  if (FUSE && tid < 128) { s_as[tid] = 0.f; s_ad[tid] = 0.f; }

  const int sr = tid >> 2, sd = tid & 3;
  const int ss = sd ^ ((sr >> 1) & 3);
  const u16* aS0 = A + (size_t)min(bm + sr,      M - 1) * K + ss * 8;
  const u16* aS1 = A + (size_t)min(bm + 64 + sr, M - 1) * K + ss * 8;
  const u16* bS0 = B + (size_t)(bn + sr)      * K + ss * 8;
  const u16* bS1 = B + (size_t)(bn + 64 + sr) * K + ss * 8;
  u16* lA0 = &As[0][0] + (size_t)(tid & ~63) * 8;
  u16* lA1 = lA0 + 2048;
  u16* lB0 = &Bs[0][0] + (size_t)(tid & ~63) * 8;
  u16* lB1 = lB0 + 2048;

  f32x4 acc[4][4];
  #pragma unroll
  for (int m = 0; m < 4; ++m)
    #pragma unroll
    for (int n = 0; n < 4; ++n)
      #pragma unroll
      for (int j = 0; j < 4; ++j) acc[m][n][j] = 0.f;

  const int nK = K >> 5;
  for (int kt = 0; kt < nK; ++kt) {
    const int ko = kt * 32;
    gload16(aS0 + ko, lA0);
    gload16(aS1 + ko, lA1);
    gload16(bS0 + ko, lB0);
    gload16(bS1 + ko, lB1);
    __syncthreads();
    bf16x8 af[4], bfr[4];
    #pragma unroll
    for (int m = 0; m < 4; ++m) {
      int row = wr + m * 16 + l15;
      af[m] = *(const bf16x8*)&As[row][(g ^ ((row >> 1) & 3)) * 8];
      int rowb = wc + m * 16 + l15;
      bfr[m] = *(const bf16x8*)&Bs[rowb][(g ^ ((rowb >> 1) & 3)) * 8];
    }
    #pragma unroll
    for (int m = 0; m < 4; ++m)
      #pragma unroll
      for (int n = 0; n < 4; ++n)
        acc[m][n] = __builtin_amdgcn_mfma_f32_16x16x32_bf16(af[m], bfr[n], acc[m][n], 0, 0, 0);
    __syncthreads();
  }
  #pragma unroll
  for (int m = 0; m < 4; ++m) {
    int row0 = bm + wr + m * 16 + g * 4;
    #pragma unroll
    for (int n = 0; n < 4; ++n) {
      int col = bn + wc + n * 16 + l15;
      float bv = bias ? bias[col] : 0.f;
      #pragma unroll
      for (int j = 0; j < 4; ++j) {
        int row = row0 + j;
        if (row < M) {
          float v = acc[m][n][j] + bv;
          if (OBF) ((u16*)Cout)[(size_t)row * Nt + col] = f2b(v);
          else     ((float*)Cout)[(size_t)row * Nt + col] = v;
        }
      }
    }
  }
  if (FUSE) {
    float ps[4][4], pd[4][4];
    #pragma unroll
    for (int m = 0; m < 4; ++m)
      #pragma unroll
      for (int j = 0; j < 4; ++j) { ps[m][j] = 0.f; pd[m][j] = 0.f; }
    #pragma unroll
    for (int n = 0; n < 4; ++n) {
      int cl = wc + n * 16 + l15;
      float wsv = attS[bn + cl], wdv = attD[bn + cl];
      #pragma unroll
      for (int m = 0; m < 4; ++m)
        #pragma unroll
        for (int j = 0; j < 4; ++j) {
          ps[m][j] = fmaf(acc[m][n][j], wsv, ps[m][j]);
          pd[m][j] = fmaf(acc[m][n][j], wdv, pd[m][j]);
        }
    }
    #pragma unroll
    for (int m = 0; m < 4; ++m)
      #pragma unroll
      for (int j = 0; j < 4; ++j)
        #pragma unroll
        for (int msk = 8; msk >= 1; msk >>= 1) {
          ps[m][j] += __shfl_xor(ps[m][j], msk);
          pd[m][j] += __shfl_xor(pd[m][j], msk);
        }
    if (l15 == 0) {
      #pragma unroll
      for (int m = 0; m < 4; ++m)
        #pragma unroll
        for (int j = 0; j < 4; ++j) {
          atomicAdd(&s_as[wr + m * 16 + g * 4 + j], ps[m][j]);
          atomicAdd(&s_ad[wr + m * 16 + g * 4 + j], pd[m][j]);
        }
    }
    __syncthreads();
    if (tid < 128) {
      int row = bm + tid;
      if (row < M) {
        int h = bn >> 7;
        asrc[(size_t)row * 4 + h] = s_as[tid];
        adst[(size_t)row * 4 + h] = s_ad[tid];
      }
    }
  }
}

// ---------------------------------------------------------------------------
// fp32 -> bf16 convert, 8 elems/thread (n % 8 == 0)
// ---------------------------------------------------------------------------
__global__ void convert_f32_bf16(const float* __restrict__ src, u16* __restrict__ dst, int n) {
  int i = (blockIdx.x * 256 + threadIdx.x) * 8;
  if (i >= n) return;
  float4 v0 = *(const float4*)(src + i);
  float4 v1 = *(const float4*)(src + i + 4);
  bf16x8 o;
  o[0] = (short)f2b(v0.x); o[1] = (short)f2b(v0.y);
  o[2] = (short)f2b(v0.z); o[3] = (short)f2b(v0.w);
  o[4] = (short)f2b(v1.x); o[5] = (short)f2b(v1.y);
  o[6] = (short)f2b(v1.z); o[7] = (short)f2b(v1.w);
  *(bf16x8*)(dst + i) = o;
}

// merged small-weight converts: W_ih, W_hh, W_att_in, W_att_out (8 elems/thr)
__global__ void convert_weights(const float* __restrict__ w_ih, const float* __restrict__ w_hh,
                                const float* __restrict__ w_in, const float* __restrict__ w_out,
                                u16* __restrict__ wihb, u16* __restrict__ whhb,
                                u16* __restrict__ winb, u16* __restrict__ woutb)
{
  int i = blockIdx.x * 256 + threadIdx.x;   // 18432 threads
  const float* src; u16* dst; int base;
  if      (i < 6144)  { src = w_ih;  dst = wihb;  base = i; }
  else if (i < 12288) { src = w_hh;  dst = whhb;  base = i - 6144; }
  else if (i < 14336) { src = w_in;  dst = winb;  base = i - 12288; }
  else                { src = w_out; dst = woutb; base = i - 14336; }
  int o = base * 8;
  float4 v0 = *(const float4*)(src + o);
  float4 v1 = *(const float4*)(src + o + 4);
  bf16x8 ov;
  ov[0] = (short)f2b(v0.x); ov[1] = (short)f2b(v0.y);
  ov[2] = (short)f2b(v0.z); ov[3] = (short)f2b(v0.w);
  ov[4] = (short)f2b(v1.x); ov[5] = (short)f2b(v1.y);
  ov[6] = (short)f2b(v1.z); ov[7] = (short)f2b(v1.w);
  *(bf16x8*)(dst + o) = ov;
}

__global__ void conv_transpose_wgat(const float* __restrict__ src, u16* __restrict__ dst) {
  int idx = blockIdx.x * 256 + threadIdx.x;
  if (idx >= KC * F_INC) return;
  int n = idx >> 8, k = idx & 255;
  dst[(size_t)n * F_INC + k] = f2b(src[(size_t)k * KC + n]);
}

// ---------------------------------------------------------------------------
// Batched edge counting-sort (all T at once)
// ---------------------------------------------------------------------------
__global__ void count_kernel(const int* __restrict__ graph, int* __restrict__ counts) {
  int e = blockIdx.x * 256 + threadIdx.x;
  int t = blockIdx.y;
  if (e < N_EDGES) {
    int d = graph[(size_t)t * 2 * N_EDGES + N_EDGES + e];
    atomicAdd(&counts[t * N_NODES + d], 1);
  }
}

__global__ __launch_bounds__(1024) void scan_kernel(
    const int* __restrict__ counts, int* __restrict__ offs)
{
  const int t = blockIdx.x;
  const int tid = threadIdx.x, lane = tid & 63, w = tid >> 6;
  __shared__ int s_wt[16];
  int carry = 0;
  const int base_abs = t * SEG;
  for (int base = 0; base < N_NODES; base += 1024) {
    int i = base + tid;
    int v = (i < N_NODES) ? (counts[t * N_NODES + i] + 1) : 0;  // +1 self loop
    int x = v;
    #pragma unroll
    for (int d = 1; d < 64; d <<= 1) {
      int nvl = __shfl_up(x, d, 64);
      if (lane >= d) x += nvl;
    }
    if (lane == 63) s_wt[w] = x;
    __syncthreads();
    if (tid < 16) {
      int y = s_wt[tid];
      #pragma unroll
      for (int d = 1; d < 16; d <<= 1) {
        int nvl = __shfl_up(y, d, 64);
        if (tid >= d) y += nvl;
      }
      s_wt[tid] = y;
    }
    __syncthreads();
    int wbase = (w > 0) ? s_wt[w - 1] : 0;
    int total = s_wt[15];
    if (i < N_NODES) offs[t * (N_NODES + 1) + i] = base_abs + carry + wbase + x - v;
    carry += total;
    __syncthreads();
  }
  if (tid == 0) offs[t * (N_NODES + 1) + N_NODES] = base_abs + carry;
}

__global__ void scatter_kernel(const int* __restrict__ graph, const int* __restrict__ offs,
                               int* __restrict__ cursor, int* __restrict__ ssrc)
{
  int i = blockIdx.x * 256 + threadIdx.x;
  int t = blockIdx.y;
  if (i >= SEG) return;
  int s, d;
  if (i < N_EDGES) {
    s = graph[(size_t)t * 2 * N_EDGES + i];
    d = graph[(size_t)t * 2 * N_EDGES + N_EDGES + i];
  } else {
    s = d = i - N_EDGES;
  }
  int pos = offs[t * (N_NODES + 1) + d] + atomicAdd(&cursor[t * N_NODES + d], 1);
  ssrc[pos] = s;
}

// ---------------------------------------------------------------------------
// Batched aggregate: one wave per (t, node); lane owns 8 contiguous channels
// of head lane>>4. Single-pass online softmax + group-of-4 STATIC-register
// lookahead on the xw gather (all indices compile-time; loads guarded by
// wave-uniform scalar branches -> no scratch, no divergence).
// ---------------------------------------------------------------------------
__global__ __launch_bounds__(256) void aggregate_kernel(
    const u16* __restrict__ xw, const float* __restrict__ a_src,
    const float* __restrict__ a_dst, const float* __restrict__ b_gat,
    const int* __restrict__ offs, const int* __restrict__ ssrc,
    u16* __restrict__ yout)
{
  const int wv = threadIdx.x >> 6, lane = threadIdx.x & 63;
  const int nd = blockIdx.x * 4 + wv;
  const int t  = blockIdx.y;
  __shared__ float s_w[4][64][4];
  __shared__ int   s_s[4][64];
  const int ob = t * (N_NODES + 1) + nd;
  const int beg = offs[ob], end = offs[ob + 1];
  const size_t rowbase = (size_t)t * N_NODES;
  const float4 adv = *(const float4*)&a_dst[(rowbase + nd) * 4];
  const int hl = lane >> 4;

  float m0=-INFINITY, m1=-INFINITY, m2=-INFINITY, m3=-INFINITY;
  float s0=0.f, s1=0.f, s2=0.f, s3=0.f;
  float acc[8] = {0.f,0.f,0.f,0.f,0.f,0.f,0.f,0.f};

  for (int base = beg; base < end; base += 64) {
    int e = base + lane;
    float a0=-INFINITY, a1=-INFINITY, a2=-INFINITY, a3=-INFINITY;
    if (e < end) {
      int s = ssrc[e];
      s_s[wv][lane] = s;
      float4 av = *(const float4*)&a_src[(rowbase + s) * 4];
      a0 = leakyf(av.x + adv.x); a1 = leakyf(av.y + adv.y);
      a2 = leakyf(av.z + adv.z); a3 = leakyf(av.w + adv.w);
    }
    float c0m=a0, c1m=a1, c2m=a2, c3m=a3;
    #pragma unroll
    for (int msk = 32; msk >= 1; msk >>= 1) {
      c0m = fmaxf(c0m, __shfl_xor(c0m, msk)); c1m = fmaxf(c1m, __shfl_xor(c1m, msk));
      c2m = fmaxf(c2m, __shfl_xor(c2m, msk)); c3m = fmaxf(c3m, __shfl_xor(c3m, msk));
    }
    float n0 = fmaxf(m0, c0m), n1 = fmaxf(m1, c1m), n2 = fmaxf(m2, c2m), n3 = fmaxf(m3, c3m);
    float sc0 = expf(m0 - n0), sc1 = expf(m1 - n1), sc2 = expf(m2 - n2), sc3 = expf(m3 - n3);
    float sch = (hl == 0) ? sc0 : (hl == 1) ? sc1 : (hl == 2) ? sc2 : sc3;
    #pragma unroll
    for (int k = 0; k < 8; ++k) acc[k] *= sch;
    float w0 = expf(a0 - n0), w1 = expf(a1 - n1), w2 = expf(a2 - n2), w3 = expf(a3 - n3);
    s_w[wv][lane][0] = w0; s_w[wv][lane][1] = w1;
    s_w[wv][lane][2] = w2; s_w[wv][lane][3] = w3;
    float t0=w0, t1=w1, t2=w2, t3=w3;
    #pragma unroll
    for (int msk = 32; msk >= 1; msk >>= 1) {
      t0 += __shfl_xor(t0, msk); t1 += __shfl_xor(t1, msk);
      t2 += __shfl_xor(t2, msk); t3 += __shfl_xor(t3, msk);
    }
    s0 = s0 * sc0 + t0; s1 = s1 * sc1 + t1;
    s2 = s2 * sc2 + t2; s3 = s3 * sc3 + t3;
    m0 = n0; m1 = n1; m2 = n2; m3 = n3;

    // ---- gather with static-register group-of-4 lookahead ----
    const int cnt = min(64, end - base);   // wave-uniform
#define LDX(j) (*(const int4*)&xw[(rowbase + s_s[wv][(j)]) * KC + lane * 8])
#define FMA8(W, X)                                                        \
    { float _w = (W);                                                     \
      acc[0] = fmaf(_w, __uint_as_float((unsigned)(X).x << 16), acc[0]);  \
      acc[1] = fmaf(_w, __uint_as_float((unsigned)(X).x & 0xffff0000u), acc[1]); \
      acc[2] = fmaf(_w, __uint_as_float((unsigned)(X).y << 16), acc[2]);  \
      acc[3] = fmaf(_w, __uint_as_float((unsigned)(X).y & 0xffff0000u), acc[3]); \
      acc[4] = fmaf(_w, __uint_as_float((unsigned)(X).z << 16), acc[4]);  \
      acc[5] = fmaf(_w, __uint_as_float((unsigned)(X).z & 0xffff0000u), acc[5]); \
      acc[6] = fmaf(_w, __uint_as_float((unsigned)(X).w << 16), acc[6]);  \
      acc[7] = fmaf(_w, __uint_as_float((unsigned)(X).w & 0xffff0000u), acc[7]); }
    int4 g0 = {0,0,0,0}, g1 = {0,0,0,0}, g2 = {0,0,0,0}, g3 = {0,0,0,0};
    if (0 < cnt) g0 = LDX(0);
    if (1 < cnt) g1 = LDX(1);
    if (2 < cnt) g2 = LDX(2);
    if (3 < cnt) g3 = LDX(3);
    for (int b4 = 0; b4 < cnt; b4 += 4) {
      int4 p0 = {0,0,0,0}, p1 = {0,0,0,0}, p2 = {0,0,0,0}, p3 = {0,0,0,0};
      if (b4 + 4 < cnt) p0 = LDX(b4 + 4);
      if (b4 + 5 < cnt) p1 = LDX(b4 + 5);
      if (b4 + 6 < cnt) p2 = LDX(b4 + 6);
      if (b4 + 7 < cnt) p3 = LDX(b4 + 7);
      {                      FMA8(s_w[wv][b4 + 0][hl], g0); }
      if (b4 + 1 < cnt)      { FMA8(s_w[wv][b4 + 1][hl], g1); }
      if (b4 + 2 < cnt)      { FMA8(s_w[wv][b4 + 2][hl], g2); }
      if (b4 + 3 < cnt)      { FMA8(s_w[wv][b4 + 3][hl], g3); }
      g0 = p0; g1 = p1; g2 = p2; g3 = p3;
    }
#undef LDX
#undef FMA8
  }
  float sh = (hl == 0) ? s0 : (hl == 1) ? s1 : (hl == 2) ? s2 : s3;
  float inv = 1.f / (sh + 1e-16f);
  #pragma unroll
  for (int k = 0; k < 8; ++k) {
    acc[k] *= inv;
    acc[k] += __shfl_xor(acc[k], 16);
    acc[k] += __shfl_xor(acc[k], 32);
  }
  if (lane < 16) {
    bf16x8 ov;
    #pragma unroll
    for (int k = 0; k < 8; ++k) {
      float v = acc[k] * 0.25f + b_gat[lane * 8 + k];
      ov[k] = (short)f2b(leakyf(v));
    }
    *(bf16x8*)&yout[(rowbase + nd) * GHD + lane * 8] = ov;
  }
}

// ---------------------------------------------------------------------------
// GRU t=0 combine (h_prev = 0, gh = b_hh); writes ctx0 bf16 + hf fp32
// ---------------------------------------------------------------------------
__global__ void gru_combine0(const u16* __restrict__ gi_t, const float* __restrict__ b_hh,
                             u16* __restrict__ ctx0, float* __restrict__ hf)
{
  int idx = blockIdx.x * 256 + threadIdx.x;
  if (idx >= N_NODES * GHD) return;
  int n = idx >> 7, c = idx & 127;
  size_t gb = (size_t)n * G3;
  float ir = b2f(gi_t[gb + c]), iz = b2f(gi_t[gb + 128 + c]), in_ = b2f(gi_t[gb + 256 + c]);
  float r = sigf(ir + b_hh[c]);
  float z = sigf(iz + b_hh[128 + c]);
  float nn = tanhf(in_ + r * b_hh[256 + c]);
  float h = (1.f - z) * nn;
  ctx0[idx] = f2b(h);
  hf[idx] = h;
}

// ---------------------------------------------------------------------------
// Fused gh-GEMM (64x384 tile) + GRU combine. A = ctx[t-1] (bf16), carry hf
// fp32 in-place; writes ctx[t] bf16 + hf. global_load_lds staging.
// ---------------------------------------------------------------------------
__global__ __launch_bounds__(256) void gru_fused(
    const u16* __restrict__ hprev, const u16* __restrict__ Whh,
    const float* __restrict__ b_hh, const u16* __restrict__ gi_t,
    float* __restrict__ hf, u16* __restrict__ ctx_out)
{
  __shared__ u16 lds[64 * 384];                       // 48 KB, dual-purpose
  u16 (*As)[32] = (u16(*)[32])lds;                    // 64 x 32
  u16 (*Bs)[32] = (u16(*)[32])(lds + 64 * 32);        // 384 x 32
  const int tid = threadIdx.x, lane = tid & 63, wv = tid >> 6;
  const int l15 = lane & 15, g = lane >> 4;
  const int bm = blockIdx.x * 64;

  const int sr = tid >> 2, sd = tid & 3;
  const int ss = sd ^ ((sr >> 1) & 3);
  const u16* aS = hprev + (size_t)min(bm + sr, N_NODES - 1) * GHD + ss * 8;
  u16* lA = lds + (size_t)(tid & ~63) * 8;
  const u16* bS[6]; u16* lB[6];
  #pragma unroll
  for (int p = 0; p < 6; ++p) {
    int r = sr + p * 64;
    bS[p] = Whh + (size_t)r * GHD + ss * 8;
    lB[p] = lds + 64 * 32 + (size_t)(p * 256 + (tid & ~63)) * 8;
  }

  f32x4 acc[4][6];
  #pragma unroll
  for (int m = 0; m < 4; ++m)
    #pragma unroll
    for (int n = 0; n < 6; ++n)
      #pragma unroll
      for (int j = 0; j < 4; ++j) acc[m][n][j] = 0.f;

  #pragma unroll
  for (int kt = 0; kt < 4; ++kt) {
    const int ko = kt * 32;
    gload16(aS + ko, lA);
    #pragma unroll
    for (int p = 0; p < 6; ++p) gload16(bS[p] + ko, lB[p]);
    __syncthreads();
    bf16x8 af[4], bfr[6];
    #pragma unroll
    for (int m = 0; m < 4; ++m) {
      int row = m * 16 + l15;
      af[m] = *(const bf16x8*)&As[row][(g ^ ((row >> 1) & 3)) * 8];
    }
    #pragma unroll
    for (int n = 0; n < 6; ++n) {
      int row = wv * 96 + n * 16 + l15;
      bfr[n] = *(const bf16x8*)&Bs[row][(g ^ ((row >> 1) & 3)) * 8];
    }
    #pragma unroll
    for (int m = 0; m < 4; ++m)
      #pragma unroll
      for (int n = 0; n < 6; ++n)
        acc[m][n] = __builtin_amdgcn_mfma_f32_16x16x32_bf16(af[m], bfr[n], acc[m][n], 0, 0, 0);
    __syncthreads();
  }
  #pragma unroll
  for (int m = 0; m < 4; ++m)
    #pragma unroll
    for (int n = 0; n < 6; ++n) {
      int c = wv * 96 + n * 16 + l15;
      float bb = b_hh[c];
      #pragma unroll
      for (int j = 0; j < 4; ++j) {
        int r = m * 16 + g * 4 + j;
        lds[r * 384 + (((c >> 3) ^ (r & 7)) << 3) + (c & 7)] = f2b(acc[m][n][j] + bb);
      }
    }
  __syncthreads();
  {
    int r = tid >> 2, gr = bm + r;
    if (gr < N_NODES) {
      const int cg = (tid & 3) * 32;
      const size_t gb = (size_t)gr * G3;
      const size_t cb = (size_t)gr * GHD;
      #pragma unroll
      for (int q = 0; q < 4; ++q) {
        int c0 = cg + q * 8;
        int sl0 = ((c0 >> 3) ^ (r & 7));
        int sl1 = (((128 + c0) >> 3) ^ (r & 7));
        int sl2 = (((256 + c0) >> 3) ^ (r & 7));
        bf16x8 hr8 = *(bf16x8*)&lds[r * 384 + sl0 * 8];
        bf16x8 hz8 = *(bf16x8*)&lds[r * 384 + sl1 * 8];
        bf16x8 hn8 = *(bf16x8*)&lds[r * 384 + sl2 * 8];
        bf16x8 ir8 = *(const bf16x8*)&gi_t[gb + c0];
        bf16x8 iz8 = *(const bf16x8*)&gi_t[gb + 128 + c0];
        bf16x8 in8 = *(const bf16x8*)&gi_t[gb + 256 + c0];
        float4 hp0 = *(const float4*)&hf[cb + c0];
        float4 hp1 = *(const float4*)&hf[cb + c0 + 4];
        float hp[8] = {hp0.x, hp0.y, hp0.z, hp0.w, hp1.x, hp1.y, hp1.z, hp1.w};
        float cv[8];
        bf16x8 hv;
        #pragma unroll
        for (int k = 0; k < 8; ++k) {
          float rr = sigf(b2f((u16)ir8[k]) + b2f((u16)hr8[k]));
          float zz = sigf(b2f((u16)iz8[k]) + b2f((u16)hz8[k]));
          float nn = tanhf(b2f((u16)in8[k]) + rr * b2f((u16)hn8[k]));
          float h = (1.f - zz) * nn + zz * hp[k];
          cv[k] = h;
          hv[k] = (short)f2b(h);
        }
        *(float4*)&hf[cb + c0]     = make_float4(cv[0], cv[1], cv[2], cv[3]);
        *(float4*)&hf[cb + c0 + 4] = make_float4(cv[4], cv[5], cv[6], cv[7]);
        *(bf16x8*)&ctx_out[cb + c0] = hv;
      }
    }
  }
}

// ---------------------------------------------------------------------------
// Temporal attention middle: scores + softmax + mix. One wave / node.
// ---------------------------------------------------------------------------
__global__ __launch_bounds__(256) void attn_mid(
    const u16* __restrict__ ctx, const float* __restrict__ q,
    u16* __restrict__ comb)
{
  const int node = blockIdx.x * 4 + (threadIdx.x >> 6);
  const int lane = threadIdx.x & 63;
  if (node >= N_NODES) return;
  const float q0 = q[(size_t)node * GHD + lane];
  const float q1 = q[(size_t)node * GHD + 64 + lane];
  float c0[T_STEPS], c1[T_STEPS], w[T_STEPS];
  float mx = -1e30f;
  #pragma unroll
  for (int t = 0; t < T_STEPS; ++t) {
    const u16* cr = ctx + ((size_t)t * N_NODES + node) * GHD;
    c0[t] = b2f(cr[lane]); c1[t] = b2f(cr[64 + lane]);
    float p = q0 * c0[t] + q1 * c1[t];
    #pragma unroll
    for (int m = 32; m >= 1; m >>= 1) p += __shfl_xor(p, m);
    w[t] = p;
    mx = fmaxf(mx, p);
  }
  float s = 0.f;
  #pragma unroll
  for (int t = 0; t < T_STEPS; ++t) { w[t] = expf(w[t] - mx); s += w[t]; }
  const float inv = 1.f / s;
  float m0 = 0.f, m1 = 0.f;
  #pragma unroll
  for (int t = 0; t < T_STEPS; ++t) { m0 = fmaf(w[t], c0[t], m0); m1 = fmaf(w[t], c1[t], m1); }
  m0 *= inv; m1 *= inv;
  u16* cb = comb + (size_t)node * 2 * GHD;
  cb[lane]       = f2b(m0);
  cb[64 + lane]  = f2b(m1);
  cb[128 + lane] = f2b(q0);
  cb[192 + lane] = f2b(q1);
}

// ---------------------------------------------------------------------------
// tanh + leaky + classifier + log_softmax. One wave / node.
// ---------------------------------------------------------------------------
__global__ __launch_bounds__(256) void logits_kernel(
    const u16* __restrict__ ao, const float* __restrict__ W_cls,
    const float* __restrict__ b_cls, float* __restrict__ out)
{
  const int node = blockIdx.x * 4 + (threadIdx.x >> 6);
  const int lane = threadIdx.x & 63;
  if (node >= N_NODES) return;
  float o0 = leakyf(tanhf(b2f(ao[(size_t)node * GHD + lane])));
  float o1 = leakyf(tanhf(b2f(ao[(size_t)node * GHD + 64 + lane])));
  float p0 = o0 * W_cls[lane] + o1 * W_cls[64 + lane];
  float p1 = o0 * W_cls[128 + lane] + o1 * W_cls[192 + lane];
  #pragma unroll
  for (int m = 32; m >= 1; m >>= 1) { p0 += __shfl_xor(p0, m); p1 += __shfl_xor(p1, m); }
  if (lane == 0) {
    float l0 = p0 + b_cls[0];
    float l1 = p1 + b_cls[1];
    float mx = fmaxf(l0, l1);
    float lse = mx + logf(expf(l0 - mx) + expf(l1 - mx));
    out[(size_t)node * 2 + 0] = l0 - lse;
    out[(size_t)node * 2 + 1] = l1 - lse;
  }
}

// ---------------------------------------------------------------------------
extern "C" void kernel_launch(void* const* d_in, const int* in_sizes, int n_in,
                              void* d_out, int out_size, void* d_ws, size_t ws_size,
                              hipStream_t stream)
{
  const int*   graph     = (const int*)  d_in[0];
  const float* fts       = (const float*)d_in[1];
  const float* W_gat     = (const float*)d_in[3];
  const float* att_src   = (const float*)d_in[4];
  const float* att_dst   = (const float*)d_in[5];
  const float* b_gat     = (const float*)d_in[6];
  const float* W_ih      = (const float*)d_in[7];
  const float* W_hh      = (const float*)d_in[8];
  const float* b_ih      = (const float*)d_in[9];
  const float* b_hh      = (const float*)d_in[10];
  const float* W_att_in  = (const float*)d_in[11];
  const float* W_att_out = (const float*)d_in[12];
  const float* W_cls     = (const float*)d_in[13];
  const float* b_cls     = (const float*)d_in[14];
  float* out = (float*)d_out;

  char* ws = (char*)d_ws;
  size_t off = 0;
  auto alloc = [&](size_t bytes) {
    void* p = ws + off;
    off = (off + bytes + 255) & ~(size_t)255;
    return p;
  };
  const size_t NT = (size_t)T_STEPS * N_NODES;      // 160000 rows
  u16*   wgatT = (u16*)alloc((size_t)KC * F_INC * 2);
  u16*   wihb  = (u16*)alloc((size_t)G3 * GHD * 2);
  u16*   whhb  = (u16*)alloc((size_t)G3 * GHD * 2);
  u16*   winb  = (u16*)alloc((size_t)GHD * GHD * 2);
  u16*   woutb = (u16*)alloc((size_t)GHD * 2 * GHD * 2);
  u16*   fbf   = (u16*)alloc(NT * F_INC * 2);       // 82 MB  fts bf16
  u16*   xw    = (u16*)alloc(NT * KC * 2);          // 164 MB
  float* asrc  = (float*)alloc(NT * 4 * 4);
  float* adst  = (float*)alloc(NT * 4 * 4);
  u16*   yall  = (u16*)alloc(NT * GHD * 2);         // 41 MB
  u16*   giall = (u16*)alloc(NT * G3 * 2);          // 123 MB
  u16*   ctx   = (u16*)alloc(NT * GHD * 2);         // 41 MB (bf16 h record)
  float* hf    = (float*)alloc((size_t)N_NODES * GHD * 4); // fp32 h carry
  float* qf    = (float*)alloc((size_t)N_NODES * GHD * 4);
  u16*   comb  = (u16*)alloc((size_t)N_NODES * 2 * GHD * 2);
  u16*   aob   = (u16*)alloc((size_t)N_NODES * GHD * 2);
  int* counts  = (int*)alloc((size_t)2 * T_STEPS * N_NODES * 4); // counts + cursor
  int* cursor  = counts + T_STEPS * N_NODES;
  int* offs    = (int*)alloc((size_t)T_STEPS * (N_NODES + 1) * 4);
  int* ssrc    = (int*)alloc((size_t)T_STEPS * SEG * 4);

  // weight converts
  conv_transpose_wgat<<<dim3((KC * F_INC + 255) / 256), 256, 0, stream>>>(W_gat, wgatT);
  convert_weights<<<dim3(72), 256, 0, stream>>>(W_ih, W_hh, W_att_in, W_att_out,
                                                wihb, whhb, winb, woutb);

  // batched edge sort
  hipMemsetAsync(counts, 0, (size_t)2 * T_STEPS * N_NODES * 4, stream);
  count_kernel<<<dim3(N_EDGES / 256, T_STEPS), 256, 0, stream>>>(graph, counts);
  scan_kernel<<<dim3(T_STEPS), 1024, 0, stream>>>(counts, offs);
  scatter_kernel<<<dim3((SEG + 255) / 256, T_STEPS), 256, 0, stream>>>(graph, offs, cursor, ssrc);

  // fts -> bf16 (one streaming pass)
  convert_f32_bf16<<<dim3((int)(NT * F_INC / 8 / 256)), 256, 0, stream>>>(
      fts, fbf, (int)(NT * F_INC));

  // xw = fbf @ W_gat^T for ALL t + fused a_src/a_dst
  gemm_bf16<1, 1><<<dim3(KC / 128, (int)(NT / 128)), 256, 0, stream>>>(
      fbf, wgatT, nullptr, xw, (int)NT, F_INC, KC, 1, att_src, att_dst, asrc, adst);

  // batched aggregate -> y for ALL t
  aggregate_kernel<<<dim3(N_NODES / 4, T_STEPS), 256, 0, stream>>>(
      xw, asrc, adst, b_gat, offs, ssrc, yall);

  // gi = y @ W_ih^T + b_ih for ALL t
  gemm_bf16<1, 0><<<dim3(G3 / 128, (int)(NT / 128)), 256, 0, stream>>>(
      yall, wihb, b_ih, giall, (int)NT, GHD, G3, 1, nullptr, nullptr, nullptr, nullptr);

  // GRU recurrence (ctx record bf16, carry fp32 in hf)
  gru_combine0<<<dim3(N_NODES * GHD / 256), 256, 0, stream>>>(giall, b_hh, ctx, hf);
  for (int t = 1; t < T_STEPS; ++t) {
    gru_fused<<<dim3((N_NODES + 63) / 64), 256, 0, stream>>>(
        ctx + (size_t)(t - 1) * N_NODES * GHD, whhb, b_hh,
        giall + (size_t)t * N_NODES * G3, hf,
        ctx + (size_t)t * N_NODES * GHD);
  }

  // temporal attention tail
  gemm_bf16<0, 0><<<dim3(1, (N_NODES + 127) / 128), 256, 0, stream>>>(
      ctx + (size_t)(T_STEPS - 1) * N_NODES * GHD, winb, nullptr, qf,
      N_NODES, GHD, GHD, 0, nullptr, nullptr, nullptr, nullptr);
  attn_mid<<<dim3(N_NODES / 4), 256, 0, stream>>>(ctx, qf, comb);
  gemm_bf16<1, 0><<<dim3(1, (N_NODES + 127) / 128), 256, 0, stream>>>(
      comb, woutb, nullptr, aob, N_NODES, 2 * GHD, GHD, 0, nullptr, nullptr, nullptr, nullptr);
  logits_kernel<<<dim3(N_NODES / 4), 256, 0, stream>>>(aob, W_cls, b_cls, out);
}

// Round 7
// 826.996 us; speedup vs baseline: 1.4315x; 1.0527x over previous
//
#include <hip/hip_runtime.h>
#include <hip/hip_bf16.h>
#include <math.h>

#define N_NODES 20000
#define N_EDGES 160000
#define T_STEPS 8
#define F_INC   256
#define HEADS   4
#define CCH     128
#define KC      512   // HEADS*CCH
#define GHD     128
#define G3      384
#define SLOPE   0.2f
#define SEG     (N_EDGES + N_NODES)   // edges + self loops per t

typedef unsigned short u16;
typedef __attribute__((ext_vector_type(8))) short bf16x8;
typedef __attribute__((ext_vector_type(4))) float f32x4;

__device__ __forceinline__ float leakyf(float x) { return x > 0.f ? x : SLOPE * x; }
__device__ __forceinline__ float b2f(u16 u) {
  union { unsigned int i; float f; } x; x.i = ((unsigned int)u) << 16; return x.f;
}
__device__ __forceinline__ u16 f2b(float f) {
  union { float f; unsigned int i; } u; u.f = f;
  unsigned int r = u.i + 0x7FFFu + ((u.i >> 16) & 1u);
  return (u16)(r >> 16);
}
__device__ __forceinline__ float sigf(float x) { return 1.f / (1.f + expf(-x)); }

// async global->LDS 16B (wave-uniform LDS base + lane*16; per-lane global src)
__device__ __forceinline__ void gload16(const void* g, void* l) {
  __builtin_amdgcn_global_load_lds(
      (const __attribute__((address_space(1))) unsigned int*)g,
      (__attribute__((address_space(3))) unsigned int*)l, 16, 0, 0);
}

// ---------------------------------------------------------------------------
// bf16 MFMA GEMM: C[M,Nt] = A[M,K] @ B^T (+bias). A (M,K) bf16, B (Nt,K) bf16.
// 256 thr / 4 waves, tile 128x128, BK=32, 16x16x32 MFMA, fp32 accum.
// global_load_lds staging, XOR slot-swizzle folded into per-lane GLOBAL src.
// swz=1: bijective XCD-chunked block swizzle. FUSE=1: fused a_src/a_dst dots.
// ---------------------------------------------------------------------------
template <int OBF, int FUSE>
__global__ __launch_bounds__(256) void gemm_bf16(
    const u16* __restrict__ A, const u16* __restrict__ B,
    const float* __restrict__ bias, void* __restrict__ Cout,
    int M, int K, int Nt, int swz,
    const float* __restrict__ attS, const float* __restrict__ attD,
    float* __restrict__ asrc, float* __restrict__ adst)
{
  __shared__ u16 As[128][32];
  __shared__ u16 Bs[128][32];
  __shared__ float s_as[128], s_ad[128];
  const int tid  = threadIdx.x;
  const int wave = tid >> 6, lane = tid & 63;
  const int wr = (wave >> 1) * 64, wc = (wave & 1) * 64;
  int bx = blockIdx.x, by = blockIdx.y;
  if (swz) {
    const int gx = gridDim.x;
    const int nwg = gx * (int)gridDim.y;
    const int lin = by * gx + bx;
    const int q = nwg >> 3, r = nwg & 7;
    const int xcd = lin & 7, idx = lin >> 3;
    const int wg = (xcd < r ? xcd * (q + 1) : r * (q + 1) + (xcd - r) * q) + idx;
    bx = wg % gx; by = wg / gx;
  }
  const int bm = by * 128, bn = bx * 128;
  const int l15 = lane & 15, g = lane >> 4;

  if (FUSE && tid < 128) { s_as[tid] = 0.f; s_ad[tid] = 0.f; }

  const int sr = tid >> 2, sd = tid & 3;
  const int ss = sd ^ ((sr >> 1) & 3);
  const u16* aS0 = A + (size_t)min(bm + sr,      M - 1) * K + ss * 8;
  const u16* aS1 = A + (size_t)min(bm + 64 + sr, M - 1) * K + ss * 8;
  const u16* bS0 = B + (size_t)(bn + sr)      * K + ss * 8;
  const u16* bS1 = B + (size_t)(bn + 64 + sr) * K + ss * 8;
  u16* lA0 = &As[0][0] + (size_t)(tid & ~63) * 8;
  u16* lA1 = lA0 + 2048;
  u16* lB0 = &Bs[0][0] + (size_t)(tid & ~63) * 8;
  u16* lB1 = lB0 + 2048;

  f32x4 acc[4][4];
  #pragma unroll
  for (int m = 0; m < 4; ++m)
    #pragma unroll
    for (int n = 0; n < 4; ++n)
      #pragma unroll
      for (int j = 0; j < 4; ++j) acc[m][n][j] = 0.f;

  const int nK = K >> 5;
  for (int kt = 0; kt < nK; ++kt) {
    const int ko = kt * 32;
    gload16(aS0 + ko, lA0);
    gload16(aS1 + ko, lA1);
    gload16(bS0 + ko, lB0);
    gload16(bS1 + ko, lB1);
    __syncthreads();
    bf16x8 af[4], bfr[4];
    #pragma unroll
    for (int m = 0; m < 4; ++m) {
      int row = wr + m * 16 + l15;
      af[m] = *(const bf16x8*)&As[row][(g ^ ((row >> 1) & 3)) * 8];
      int rowb = wc + m * 16 + l15;
      bfr[m] = *(const bf16x8*)&Bs[rowb][(g ^ ((rowb >> 1) & 3)) * 8];
    }
    #pragma unroll
    for (int m = 0; m < 4; ++m)
      #pragma unroll
      for (int n = 0; n < 4; ++n)
        acc[m][n] = __builtin_amdgcn_mfma_f32_16x16x32_bf16(af[m], bfr[n], acc[m][n], 0, 0, 0);
    __syncthreads();
  }
  #pragma unroll
  for (int m = 0; m < 4; ++m) {
    int row0 = bm + wr + m * 16 + g * 4;
    #pragma unroll
    for (int n = 0; n < 4; ++n) {
      int col = bn + wc + n * 16 + l15;
      float bv = bias ? bias[col] : 0.f;
      #pragma unroll
      for (int j = 0; j < 4; ++j) {
        int row = row0 + j;
        if (row < M) {
          float v = acc[m][n][j] + bv;
          if (OBF) ((u16*)Cout)[(size_t)row * Nt + col] = f2b(v);
          else     ((float*)Cout)[(size_t)row * Nt + col] = v;
        }
      }
    }
  }
  if (FUSE) {
    float ps[4][4], pd[4][4];
    #pragma unroll
    for (int m = 0; m < 4; ++m)
      #pragma unroll
      for (int j = 0; j < 4; ++j) { ps[m][j] = 0.f; pd[m][j] = 0.f; }
    #pragma unroll
    for (int n = 0; n < 4; ++n) {
      int cl = wc + n * 16 + l15;
      float wsv = attS[bn + cl], wdv = attD[bn + cl];
      #pragma unroll
      for (int m = 0; m < 4; ++m)
        #pragma unroll
        for (int j = 0; j < 4; ++j) {
          ps[m][j] = fmaf(acc[m][n][j], wsv, ps[m][j]);
          pd[m][j] = fmaf(acc[m][n][j], wdv, pd[m][j]);
        }
    }
    #pragma unroll
    for (int m = 0; m < 4; ++m)
      #pragma unroll
      for (int j = 0; j < 4; ++j)
        #pragma unroll
        for (int msk = 8; msk >= 1; msk >>= 1) {
          ps[m][j] += __shfl_xor(ps[m][j], msk);
          pd[m][j] += __shfl_xor(pd[m][j], msk);
        }
    if (l15 == 0) {
      #pragma unroll
      for (int m = 0; m < 4; ++m)
        #pragma unroll
        for (int j = 0; j < 4; ++j) {
          atomicAdd(&s_as[wr + m * 16 + g * 4 + j], ps[m][j]);
          atomicAdd(&s_ad[wr + m * 16 + g * 4 + j], pd[m][j]);
        }
    }
    __syncthreads();
    if (tid < 128) {
      int row = bm + tid;
      if (row < M) {
        int h = bn >> 7;
        asrc[(size_t)row * 4 + h] = s_as[tid];
        adst[(size_t)row * 4 + h] = s_ad[tid];
      }
    }
  }
}

// ---------------------------------------------------------------------------
// fp32 -> bf16 convert, 8 elems/thread (n % 8 == 0)
// ---------------------------------------------------------------------------
__global__ void convert_f32_bf16(const float* __restrict__ src, u16* __restrict__ dst, int n) {
  int i = (blockIdx.x * 256 + threadIdx.x) * 8;
  if (i >= n) return;
  float4 v0 = *(const float4*)(src + i);
  float4 v1 = *(const float4*)(src + i + 4);
  bf16x8 o;
  o[0] = (short)f2b(v0.x); o[1] = (short)f2b(v0.y);
  o[2] = (short)f2b(v0.z); o[3] = (short)f2b(v0.w);
  o[4] = (short)f2b(v1.x); o[5] = (short)f2b(v1.y);
  o[6] = (short)f2b(v1.z); o[7] = (short)f2b(v1.w);
  *(bf16x8*)(dst + i) = o;
}

// merged small-weight converts: W_ih, W_hh, W_att_in, W_att_out (8 elems/thr)
__global__ void convert_weights(const float* __restrict__ w_ih, const float* __restrict__ w_hh,
                                const float* __restrict__ w_in, const float* __restrict__ w_out,
                                u16* __restrict__ wihb, u16* __restrict__ whhb,
                                u16* __restrict__ winb, u16* __restrict__ woutb)
{
  int i = blockIdx.x * 256 + threadIdx.x;   // 18432 threads
  const float* src; u16* dst; int base;
  if      (i < 6144)  { src = w_ih;  dst = wihb;  base = i; }
  else if (i < 12288) { src = w_hh;  dst = whhb;  base = i - 6144; }
  else if (i < 14336) { src = w_in;  dst = winb;  base = i - 12288; }
  else                { src = w_out; dst = woutb; base = i - 14336; }
  int o = base * 8;
  float4 v0 = *(const float4*)(src + o);
  float4 v1 = *(const float4*)(src + o + 4);
  bf16x8 ov;
  ov[0] = (short)f2b(v0.x); ov[1] = (short)f2b(v0.y);
  ov[2] = (short)f2b(v0.z); ov[3] = (short)f2b(v0.w);
  ov[4] = (short)f2b(v1.x); ov[5] = (short)f2b(v1.y);
  ov[6] = (short)f2b(v1.z); ov[7] = (short)f2b(v1.w);
  *(bf16x8*)(dst + o) = ov;
}

__global__ void conv_transpose_wgat(const float* __restrict__ src, u16* __restrict__ dst) {
  int idx = blockIdx.x * 256 + threadIdx.x;
  if (idx >= KC * F_INC) return;
  int n = idx >> 8, k = idx & 255;
  dst[(size_t)n * F_INC + k] = f2b(src[(size_t)k * KC + n]);
}

// ---------------------------------------------------------------------------
// Batched edge counting-sort (all T at once)
// ---------------------------------------------------------------------------
__global__ void count_kernel(const int* __restrict__ graph, int* __restrict__ counts) {
  int e = blockIdx.x * 256 + threadIdx.x;
  int t = blockIdx.y;
  if (e < N_EDGES) {
    int d = graph[(size_t)t * 2 * N_EDGES + N_EDGES + e];
    atomicAdd(&counts[t * N_NODES + d], 1);
  }
}

__global__ __launch_bounds__(1024) void scan_kernel(
    const int* __restrict__ counts, int* __restrict__ offs)
{
  const int t = blockIdx.x;
  const int tid = threadIdx.x, lane = tid & 63, w = tid >> 6;
  __shared__ int s_wt[16];
  int carry = 0;
  const int base_abs = t * SEG;
  for (int base = 0; base < N_NODES; base += 1024) {
    int i = base + tid;
    int v = (i < N_NODES) ? (counts[t * N_NODES + i] + 1) : 0;  // +1 self loop
    int x = v;
    #pragma unroll
    for (int d = 1; d < 64; d <<= 1) {
      int nvl = __shfl_up(x, d, 64);
      if (lane >= d) x += nvl;
    }
    if (lane == 63) s_wt[w] = x;
    __syncthreads();
    if (tid < 16) {
      int y = s_wt[tid];
      #pragma unroll
      for (int d = 1; d < 16; d <<= 1) {
        int nvl = __shfl_up(y, d, 64);
        if (tid >= d) y += nvl;
      }
      s_wt[tid] = y;
    }
    __syncthreads();
    int wbase = (w > 0) ? s_wt[w - 1] : 0;
    int total = s_wt[15];
    if (i < N_NODES) offs[t * (N_NODES + 1) + i] = base_abs + carry + wbase + x - v;
    carry += total;
    __syncthreads();
  }
  if (tid == 0) offs[t * (N_NODES + 1) + N_NODES] = base_abs + carry;
}

__global__ void scatter_kernel(const int* __restrict__ graph, const int* __restrict__ offs,
                               int* __restrict__ cursor, int* __restrict__ ssrc)
{
  int i = blockIdx.x * 256 + threadIdx.x;
  int t = blockIdx.y;
  if (i >= SEG) return;
  int s, d;
  if (i < N_EDGES) {
    s = graph[(size_t)t * 2 * N_EDGES + i];
    d = graph[(size_t)t * 2 * N_EDGES + N_EDGES + i];
  } else {
    s = d = i - N_EDGES;
  }
  int pos = offs[t * (N_NODES + 1) + d] + atomicAdd(&cursor[t * N_NODES + d], 1);
  ssrc[pos] = s;
}

// ---------------------------------------------------------------------------
// Batched aggregate: one wave per (t, node). Head-interleaved online softmax:
// lane = (edge<<2)|head, 16-edge chunks, reduce over XOR{4,8,16,32} = 8
// shuffles/chunk. Gather: pad cnt to x4, branch-free 8-wide + 4-tail static
// lookahead (padded edges carry weight 0 and a valid duplicate src row).
// Zero LDS; all cross-phase data moves via __shfl.
// ---------------------------------------------------------------------------
__global__ __launch_bounds__(256) void aggregate_kernel(
    const u16* __restrict__ xw, const float* __restrict__ a_src,
    const float* __restrict__ a_dst, const float* __restrict__ b_gat,
    const int* __restrict__ offs, const int* __restrict__ ssrc,
    u16* __restrict__ yout)
{
  const int wv = threadIdx.x >> 6, lane = threadIdx.x & 63;
  const int nd = blockIdx.x * 4 + wv;
  const int t  = blockIdx.y;
  const int ob = t * (N_NODES + 1) + nd;
  const int beg = offs[ob], end = offs[ob + 1];
  const size_t rowbase = (size_t)t * N_NODES;
  const int he   = lane & 3;    // head (softmax phase)
  const int eidx = lane >> 2;   // edge slot 0..15 (softmax phase)
  const int hl   = lane >> 4;   // head (gather phase, channel-major)
  const float advh = a_dst[(rowbase + nd) * 4 + he];

  float m = -INFINITY, ssum = 0.f;
  float acc[8] = {0.f,0.f,0.f,0.f,0.f,0.f,0.f,0.f};

#define FMA8(W, X)                                                        \
    { float _w = (W);                                                     \
      acc[0] = fmaf(_w, __uint_as_float((unsigned)(X).x << 16), acc[0]);  \
      acc[1] = fmaf(_w, __uint_as_float((unsigned)(X).x & 0xffff0000u), acc[1]); \
      acc[2] = fmaf(_w, __uint_as_float((unsigned)(X).y << 16), acc[2]);  \
      acc[3] = fmaf(_w, __uint_as_float((unsigned)(X).y & 0xffff0000u), acc[3]); \
      acc[4] = fmaf(_w, __uint_as_float((unsigned)(X).z << 16), acc[4]);  \
      acc[5] = fmaf(_w, __uint_as_float((unsigned)(X).z & 0xffff0000u), acc[5]); \
      acc[6] = fmaf(_w, __uint_as_float((unsigned)(X).w << 16), acc[6]);  \
      acc[7] = fmaf(_w, __uint_as_float((unsigned)(X).w & 0xffff0000u), acc[7]); }
#define LDE(SVAR) (*(const int4*)&xw[(rowbase + (SVAR)) * KC + lane * 8])

  for (int base = beg; base < end; base += 16) {
    const int cnt = min(16, end - base);          // wave-uniform
    const int e = base + eidx;
    // padded lanes read a valid duplicate row (edge 'beg of chunk')
    const int sidx = (e < end) ? ssrc[e] : ssrc[base];
    const float av = a_src[(rowbase + sidx) * 4 + he];
    const float a = (eidx < cnt) ? leakyf(av + advh) : -INFINITY;
    // chunk max per head (reduce over edge slots)
    float cm = a;
    cm = fmaxf(cm, __shfl_xor(cm, 4));
    cm = fmaxf(cm, __shfl_xor(cm, 8));
    cm = fmaxf(cm, __shfl_xor(cm, 16));
    cm = fmaxf(cm, __shfl_xor(cm, 32));
    const float nm = fmaxf(m, cm);
    const float sc = expf(m - nm);                // acc rescale for head 'he'
    const float w = expf(a - nm);                 // 0 for padded lanes
    float ts = w;
    ts += __shfl_xor(ts, 4);
    ts += __shfl_xor(ts, 8);
    ts += __shfl_xor(ts, 16);
    ts += __shfl_xor(ts, 32);
    ssum = ssum * sc + ts;
    m = nm;
    // rescale accumulator by my gather-head's factor
    const float schl = __shfl(sc, hl);
    #pragma unroll
    for (int k = 0; k < 8; ++k) acc[k] *= schl;

    // ---- branch-free padded gather: 8-wide + 4-tail ----
    const int cpad = (cnt + 3) & ~3;              // 4..16, wave-uniform
    int b4 = 0;
    for (; b4 + 8 <= cpad; b4 += 8) {
      const int s0 = __shfl(sidx, (b4 + 0) << 2);
      const int s1 = __shfl(sidx, (b4 + 1) << 2);
      const int s2 = __shfl(sidx, (b4 + 2) << 2);
      const int s3 = __shfl(sidx, (b4 + 3) << 2);
      const int s4 = __shfl(sidx, (b4 + 4) << 2);
      const int s5 = __shfl(sidx, (b4 + 5) << 2);
      const int s6 = __shfl(sidx, (b4 + 6) << 2);
      const int s7 = __shfl(sidx, (b4 + 7) << 2);
      const int4 x0 = LDE(s0); const int4 x1 = LDE(s1);
      const int4 x2 = LDE(s2); const int4 x3 = LDE(s3);
      const int4 x4 = LDE(s4); const int4 x5 = LDE(s5);
      const int4 x6 = LDE(s6); const int4 x7 = LDE(s7);
      const float w0 = __shfl(w, ((b4 + 0) << 2) + hl);
      const float w1 = __shfl(w, ((b4 + 1) << 2) + hl);
      const float w2 = __shfl(w, ((b4 + 2) << 2) + hl);
      const float w3 = __shfl(w, ((b4 + 3) << 2) + hl);
      const float w4 = __shfl(w, ((b4 + 4) << 2) + hl);
      const float w5 = __shfl(w, ((b4 + 5) << 2) + hl);
      const float w6 = __shfl(w, ((b4 + 6) << 2) + hl);
      const float w7 = __shfl(w, ((b4 + 7) << 2) + hl);
      FMA8(w0, x0); FMA8(w1, x1); FMA8(w2, x2); FMA8(w3, x3);
      FMA8(w4, x4); FMA8(w5, x5); FMA8(w6, x6); FMA8(w7, x7);
    }
    if (b4 < cpad) {   // exactly 4 remain
      const int s0 = __shfl(sidx, (b4 + 0) << 2);
      const int s1 = __shfl(sidx, (b4 + 1) << 2);
      const int s2 = __shfl(sidx, (b4 + 2) << 2);
      const int s3 = __shfl(sidx, (b4 + 3) << 2);
      const int4 x0 = LDE(s0); const int4 x1 = LDE(s1);
      const int4 x2 = LDE(s2); const int4 x3 = LDE(s3);
      const float w0 = __shfl(w, ((b4 + 0) << 2) + hl);
      const float w1 = __shfl(w, ((b4 + 1) << 2) + hl);
      const float w2 = __shfl(w, ((b4 + 2) << 2) + hl);
      const float w3 = __shfl(w, ((b4 + 3) << 2) + hl);
      FMA8(w0, x0); FMA8(w1, x1); FMA8(w2, x2); FMA8(w3, x3);
    }
  }
#undef LDE
#undef FMA8

  // normalize by my gather-head's sum (held in lane hl), mean over heads
  const float sh = __shfl(ssum, hl);
  const float inv = 1.f / (sh + 1e-16f);
  #pragma unroll
  for (int k = 0; k < 8; ++k) {
    acc[k] *= inv;
    acc[k] += __shfl_xor(acc[k], 16);
    acc[k] += __shfl_xor(acc[k], 32);
  }
  if (lane < 16) {
    bf16x8 ov;
    #pragma unroll
    for (int k = 0; k < 8; ++k) {
      float v = acc[k] * 0.25f + b_gat[lane * 8 + k];
      ov[k] = (short)f2b(leakyf(v));
    }
    *(bf16x8*)&yout[(rowbase + nd) * GHD + lane * 8] = ov;
  }
}

// ---------------------------------------------------------------------------
// GRU t=0 combine (h_prev = 0, gh = b_hh); writes ctx0 bf16 + hf fp32
// ---------------------------------------------------------------------------
__global__ void gru_combine0(const u16* __restrict__ gi_t, const float* __restrict__ b_hh,
                             u16* __restrict__ ctx0, float* __restrict__ hf)
{
  int idx = blockIdx.x * 256 + threadIdx.x;
  if (idx >= N_NODES * GHD) return;
  int n = idx >> 7, c = idx & 127;
  size_t gb = (size_t)n * G3;
  float ir = b2f(gi_t[gb + c]), iz = b2f(gi_t[gb + 128 + c]), in_ = b2f(gi_t[gb + 256 + c]);
  float r = sigf(ir + b_hh[c]);
  float z = sigf(iz + b_hh[128 + c]);
  float nn = tanhf(in_ + r * b_hh[256 + c]);
  float h = (1.f - z) * nn;
  ctx0[idx] = f2b(h);
  hf[idx] = h;
}

// ---------------------------------------------------------------------------
// Fused gh-GEMM (64x384 tile) + GRU combine. A = ctx[t-1] (bf16), carry hf
// fp32 in-place; writes ctx[t] bf16 + hf. global_load_lds staging.
// ---------------------------------------------------------------------------
__global__ __launch_bounds__(256) void gru_fused(
    const u16* __restrict__ hprev, const u16* __restrict__ Whh,
    const float* __restrict__ b_hh, const u16* __restrict__ gi_t,
    float* __restrict__ hf, u16* __restrict__ ctx_out)
{
  __shared__ u16 lds[64 * 384];                       // 48 KB, dual-purpose
  u16 (*As)[32] = (u16(*)[32])lds;                    // 64 x 32
  u16 (*Bs)[32] = (u16(*)[32])(lds + 64 * 32);        // 384 x 32
  const int tid = threadIdx.x, lane = tid & 63, wv = tid >> 6;
  const int l15 = lane & 15, g = lane >> 4;
  const int bm = blockIdx.x * 64;

  const int sr = tid >> 2, sd = tid & 3;
  const int ss = sd ^ ((sr >> 1) & 3);
  const u16* aS = hprev + (size_t)min(bm + sr, N_NODES - 1) * GHD + ss * 8;
  u16* lA = lds + (size_t)(tid & ~63) * 8;
  const u16* bS[6]; u16* lB[6];
  #pragma unroll
  for (int p = 0; p < 6; ++p) {
    int r = sr + p * 64;
    bS[p] = Whh + (size_t)r * GHD + ss * 8;
    lB[p] = lds + 64 * 32 + (size_t)(p * 256 + (tid & ~63)) * 8;
  }

  f32x4 acc[4][6];
  #pragma unroll
  for (int m = 0; m < 4; ++m)
    #pragma unroll
    for (int n = 0; n < 6; ++n)
      #pragma unroll
      for (int j = 0; j < 4; ++j) acc[m][n][j] = 0.f;

  #pragma unroll
  for (int kt = 0; kt < 4; ++kt) {
    const int ko = kt * 32;
    gload16(aS + ko, lA);
    #pragma unroll
    for (int p = 0; p < 6; ++p) gload16(bS[p] + ko, lB[p]);
    __syncthreads();
    bf16x8 af[4], bfr[6];
    #pragma unroll
    for (int m = 0; m < 4; ++m) {
      int row = m * 16 + l15;
      af[m] = *(const bf16x8*)&As[row][(g ^ ((row >> 1) & 3)) * 8];
    }
    #pragma unroll
    for (int n = 0; n < 6; ++n) {
      int row = wv * 96 + n * 16 + l15;
      bfr[n] = *(const bf16x8*)&Bs[row][(g ^ ((row >> 1) & 3)) * 8];
    }
    #pragma unroll
    for (int m = 0; m < 4; ++m)
      #pragma unroll
      for (int n = 0; n < 6; ++n)
        acc[m][n] = __builtin_amdgcn_mfma_f32_16x16x32_bf16(af[m], bfr[n], acc[m][n], 0, 0, 0);
    __syncthreads();
  }
  #pragma unroll
  for (int m = 0; m < 4; ++m)
    #pragma unroll
    for (int n = 0; n < 6; ++n) {
      int c = wv * 96 + n * 16 + l15;
      float bb = b_hh[c];
      #pragma unroll
      for (int j = 0; j < 4; ++j) {
        int r = m * 16 + g * 4 + j;
        lds[r * 384 + (((c >> 3) ^ (r & 7)) << 3) + (c & 7)] = f2b(acc[m][n][j] + bb);
      }
    }
  __syncthreads();
  {
    int r = tid >> 2, gr = bm + r;
    if (gr < N_NODES) {
      const int cg = (tid & 3) * 32;
      const size_t gb = (size_t)gr * G3;
      const size_t cb = (size_t)gr * GHD;
      #pragma unroll
      for (int q = 0; q < 4; ++q) {
        int c0 = cg + q * 8;
        int sl0 = ((c0 >> 3) ^ (r & 7));
        int sl1 = (((128 + c0) >> 3) ^ (r & 7));
        int sl2 = (((256 + c0) >> 3) ^ (r & 7));
        bf16x8 hr8 = *(bf16x8*)&lds[r * 384 + sl0 * 8];
        bf16x8 hz8 = *(bf16x8*)&lds[r * 384 + sl1 * 8];
        bf16x8 hn8 = *(bf16x8*)&lds[r * 384 + sl2 * 8];
        bf16x8 ir8 = *(const bf16x8*)&gi_t[gb + c0];
        bf16x8 iz8 = *(const bf16x8*)&gi_t[gb + 128 + c0];
        bf16x8 in8 = *(const bf16x8*)&gi_t[gb + 256 + c0];
        float4 hp0 = *(const float4*)&hf[cb + c0];
        float4 hp1 = *(const float4*)&hf[cb + c0 + 4];
        float hp[8] = {hp0.x, hp0.y, hp0.z, hp0.w, hp1.x, hp1.y, hp1.z, hp1.w};
        float cv[8];
        bf16x8 hv;
        #pragma unroll
        for (int k = 0; k < 8; ++k) {
          float rr = sigf(b2f((u16)ir8[k]) + b2f((u16)hr8[k]));
          float zz = sigf(b2f((u16)iz8[k]) + b2f((u16)hz8[k]));
          float nn = tanhf(b2f((u16)in8[k]) + rr * b2f((u16)hn8[k]));
          float h = (1.f - zz) * nn + zz * hp[k];
          cv[k] = h;
          hv[k] = (short)f2b(h);
        }
        *(float4*)&hf[cb + c0]     = make_float4(cv[0], cv[1], cv[2], cv[3]);
        *(float4*)&hf[cb + c0 + 4] = make_float4(cv[4], cv[5], cv[6], cv[7]);
        *(bf16x8*)&ctx_out[cb + c0] = hv;
      }
    }
  }
}

// ---------------------------------------------------------------------------
// Temporal attention middle: scores + softmax + mix. One wave / node.
// ---------------------------------------------------------------------------
__global__ __launch_bounds__(256) void attn_mid(
    const u16* __restrict__ ctx, const float* __restrict__ q,
    u16* __restrict__ comb)
{
  const int node = blockIdx.x * 4 + (threadIdx.x >> 6);
  const int lane = threadIdx.x & 63;
  if (node >= N_NODES) return;
  const float q0 = q[(size_t)node * GHD + lane];
  const float q1 = q[(size_t)node * GHD + 64 + lane];
  float c0[T_STEPS], c1[T_STEPS], w[T_STEPS];
  float mx = -1e30f;
  #pragma unroll
  for (int t = 0; t < T_STEPS; ++t) {
    const u16* cr = ctx + ((size_t)t * N_NODES + node) * GHD;
    c0[t] = b2f(cr[lane]); c1[t] = b2f(cr[64 + lane]);
    float p = q0 * c0[t] + q1 * c1[t];
    #pragma unroll
    for (int m = 32; m >= 1; m >>= 1) p += __shfl_xor(p, m);
    w[t] = p;
    mx = fmaxf(mx, p);
  }
  float s = 0.f;
  #pragma unroll
  for (int t = 0; t < T_STEPS; ++t) { w[t] = expf(w[t] - mx); s += w[t]; }
  const float inv = 1.f / s;
  float m0 = 0.f, m1 = 0.f;
  #pragma unroll
  for (int t = 0; t < T_STEPS; ++t) { m0 = fmaf(w[t], c0[t], m0); m1 = fmaf(w[t], c1[t], m1); }
  m0 *= inv; m1 *= inv;
  u16* cb = comb + (size_t)node * 2 * GHD;
  cb[lane]       = f2b(m0);
  cb[64 + lane]  = f2b(m1);
  cb[128 + lane] = f2b(q0);
  cb[192 + lane] = f2b(q1);
}

// ---------------------------------------------------------------------------
// tanh + leaky + classifier + log_softmax. One wave / node.
// ---------------------------------------------------------------------------
__global__ __launch_bounds__(256) void logits_kernel(
    const u16* __restrict__ ao, const float* __restrict__ W_cls,
    const float* __restrict__ b_cls, float* __restrict__ out)
{
  const int node = blockIdx.x * 4 + (threadIdx.x >> 6);
  const int lane = threadIdx.x & 63;
  if (node >= N_NODES) return;
  float o0 = leakyf(tanhf(b2f(ao[(size_t)node * GHD + lane])));
  float o1 = leakyf(tanhf(b2f(ao[(size_t)node * GHD + 64 + lane])));
  float p0 = o0 * W_cls[lane] + o1 * W_cls[64 + lane];
  float p1 = o0 * W_cls[128 + lane] + o1 * W_cls[192 + lane];
  #pragma unroll
  for (int m = 32; m >= 1; m >>= 1) { p0 += __shfl_xor(p0, m); p1 += __shfl_xor(p1, m); }
  if (lane == 0) {
    float l0 = p0 + b_cls[0];
    float l1 = p1 + b_cls[1];
    float mx = fmaxf(l0, l1);
    float lse = mx + logf(expf(l0 - mx) + expf(l1 - mx));
    out[(size_t)node * 2 + 0] = l0 - lse;
    out[(size_t)node * 2 + 1] = l1 - lse;
  }
}

// ---------------------------------------------------------------------------
extern "C" void kernel_launch(void* const* d_in, const int* in_sizes, int n_in,
                              void* d_out, int out_size, void* d_ws, size_t ws_size,
                              hipStream_t stream)
{
  const int*   graph     = (const int*)  d_in[0];
  const float* fts       = (const float*)d_in[1];
  const float* W_gat     = (const float*)d_in[3];
  const float* att_src   = (const float*)d_in[4];
  const float* att_dst   = (const float*)d_in[5];
  const float* b_gat     = (const float*)d_in[6];
  const float* W_ih      = (const float*)d_in[7];
  const float* W_hh      = (const float*)d_in[8];
  const float* b_ih      = (const float*)d_in[9];
  const float* b_hh      = (const float*)d_in[10];
  const float* W_att_in  = (const float*)d_in[11];
  const float* W_att_out = (const float*)d_in[12];
  const float* W_cls     = (const float*)d_in[13];
  const float* b_cls     = (const float*)d_in[14];
  float* out = (float*)d_out;

  char* ws = (char*)d_ws;
  size_t off = 0;
  auto alloc = [&](size_t bytes) {
    void* p = ws + off;
    off = (off + bytes + 255) & ~(size_t)255;
    return p;
  };
  const size_t NT = (size_t)T_STEPS * N_NODES;      // 160000 rows
  u16*   wgatT = (u16*)alloc((size_t)KC * F_INC * 2);
  u16*   wihb  = (u16*)alloc((size_t)G3 * GHD * 2);
  u16*   whhb  = (u16*)alloc((size_t)G3 * GHD * 2);
  u16*   winb  = (u16*)alloc((size_t)GHD * GHD * 2);
  u16*   woutb = (u16*)alloc((size_t)GHD * 2 * GHD * 2);
  u16*   fbf   = (u16*)alloc(NT * F_INC * 2);       // 82 MB  fts bf16
  u16*   xw    = (u16*)alloc(NT * KC * 2);          // 164 MB
  float* asrc  = (float*)alloc(NT * 4 * 4);
  float* adst  = (float*)alloc(NT * 4 * 4);
  u16*   yall  = (u16*)alloc(NT * GHD * 2);         // 41 MB
  u16*   giall = (u16*)alloc(NT * G3 * 2);          // 123 MB
  u16*   ctx   = (u16*)alloc(NT * GHD * 2);         // 41 MB (bf16 h record)
  float* hf    = (float*)alloc((size_t)N_NODES * GHD * 4); // fp32 h carry
  float* qf    = (float*)alloc((size_t)N_NODES * GHD * 4);
  u16*   comb  = (u16*)alloc((size_t)N_NODES * 2 * GHD * 2);
  u16*   aob   = (u16*)alloc((size_t)N_NODES * GHD * 2);
  int* counts  = (int*)alloc((size_t)2 * T_STEPS * N_NODES * 4); // counts + cursor
  int* cursor  = counts + T_STEPS * N_NODES;
  int* offs    = (int*)alloc((size_t)T_STEPS * (N_NODES + 1) * 4);
  int* ssrc    = (int*)alloc((size_t)T_STEPS * SEG * 4);

  // weight converts
  conv_transpose_wgat<<<dim3((KC * F_INC + 255) / 256), 256, 0, stream>>>(W_gat, wgatT);
  convert_weights<<<dim3(72), 256, 0, stream>>>(W_ih, W_hh, W_att_in, W_att_out,
                                                wihb, whhb, winb, woutb);

  // batched edge sort
  hipMemsetAsync(counts, 0, (size_t)2 * T_STEPS * N_NODES * 4, stream);
  count_kernel<<<dim3(N_EDGES / 256, T_STEPS), 256, 0, stream>>>(graph, counts);
  scan_kernel<<<dim3(T_STEPS), 1024, 0, stream>>>(counts, offs);
  scatter_kernel<<<dim3((SEG + 255) / 256, T_STEPS), 256, 0, stream>>>(graph, offs, cursor, ssrc);

  // fts -> bf16 (one streaming pass)
  convert_f32_bf16<<<dim3((int)(NT * F_INC / 8 / 256)), 256, 0, stream>>>(
      fts, fbf, (int)(NT * F_INC));

  // xw = fbf @ W_gat^T for ALL t + fused a_src/a_dst
  gemm_bf16<1, 1><<<dim3(KC / 128, (int)(NT / 128)), 256, 0, stream>>>(
      fbf, wgatT, nullptr, xw, (int)NT, F_INC, KC, 1, att_src, att_dst, asrc, adst);

  // batched aggregate -> y for ALL t
  aggregate_kernel<<<dim3(N_NODES / 4, T_STEPS), 256, 0, stream>>>(
      xw, asrc, adst, b_gat, offs, ssrc, yall);

  // gi = y @ W_ih^T + b_ih for ALL t
  gemm_bf16<1, 0><<<dim3(G3 / 128, (int)(NT / 128)), 256, 0, stream>>>(
      yall, wihb, b_ih, giall, (int)NT, GHD, G3, 1, nullptr, nullptr, nullptr, nullptr);

  // GRU recurrence (ctx record bf16, carry fp32 in hf)
  gru_combine0<<<dim3(N_NODES * GHD / 256), 256, 0, stream>>>(giall, b_hh, ctx, hf);
  for (int t = 1; t < T_STEPS; ++t) {
    gru_fused<<<dim3((N_NODES + 63) / 64), 256, 0, stream>>>(
        ctx + (size_t)(t - 1) * N_NODES * GHD, whhb, b_hh,
        giall + (size_t)t * N_NODES * G3, hf,
        ctx + (size_t)t * N_NODES * GHD);
  }

  // temporal attention tail
  gemm_bf16<0, 0><<<dim3(1, (N_NODES + 127) / 128), 256, 0, stream>>>(
      ctx + (size_t)(T_STEPS - 1) * N_NODES * GHD, winb, nullptr, qf,
      N_NODES, GHD, GHD, 0, nullptr, nullptr, nullptr, nullptr);
  attn_mid<<<dim3(N_NODES / 4), 256, 0, stream>>>(ctx, qf, comb);
  gemm_bf16<1, 0><<<dim3(1, (N_NODES + 127) / 128), 256, 0, stream>>>(
      comb, woutb, nullptr, aob, N_NODES, 2 * GHD, GHD, 0, nullptr, nullptr, nullptr, nullptr);
  logits_kernel<<<dim3(N_NODES / 4), 256, 0, stream>>>(aob, W_cls, b_cls, out);
}

// Round 8
// 744.392 us; speedup vs baseline: 1.5904x; 1.1110x over previous
//
#include <hip/hip_runtime.h>
#include <hip/hip_bf16.h>
#include <math.h>

#define N_NODES 20000
#define N_EDGES 160000
#define T_STEPS 8
#define F_INC   256
#define HEADS   4
#define CCH     128
#define KC      512   // HEADS*CCH
#define GHD     128
#define G3      384
#define SLOPE   0.2f
#define SEG     (N_EDGES + N_NODES)   // edges + self loops per t

typedef unsigned short u16;
typedef __attribute__((ext_vector_type(8))) short bf16x8;
typedef __attribute__((ext_vector_type(4))) float f32x4;

__device__ __forceinline__ float leakyf(float x) { return x > 0.f ? x : SLOPE * x; }
__device__ __forceinline__ float b2f(u16 u) {
  union { unsigned int i; float f; } x; x.i = ((unsigned int)u) << 16; return x.f;
}
__device__ __forceinline__ u16 f2b(float f) {
  union { float f; unsigned int i; } u; u.f = f;
  unsigned int r = u.i + 0x7FFFu + ((u.i >> 16) & 1u);
  return (u16)(r >> 16);
}
__device__ __forceinline__ float sigf(float x) { return 1.f / (1.f + expf(-x)); }

// async global->LDS 16B (wave-uniform LDS base + lane*16; per-lane global src)
__device__ __forceinline__ void gload16(const void* g, void* l) {
  __builtin_amdgcn_global_load_lds(
      (const __attribute__((address_space(1))) unsigned int*)g,
      (__attribute__((address_space(3))) unsigned int*)l, 16, 0, 0);
}

// pack 8 f32 -> bf16x8 via v_cvt_pk_bf16_f32 (no builtin on gfx950)
__device__ __forceinline__ bf16x8 cvt8(f32x4 lo, f32x4 hi) {
  union { unsigned int u[4]; bf16x8 v; } r;
  asm("v_cvt_pk_bf16_f32 %0, %1, %2" : "=v"(r.u[0]) : "v"(lo[0]), "v"(lo[1]));
  asm("v_cvt_pk_bf16_f32 %0, %1, %2" : "=v"(r.u[1]) : "v"(lo[2]), "v"(lo[3]));
  asm("v_cvt_pk_bf16_f32 %0, %1, %2" : "=v"(r.u[2]) : "v"(hi[0]), "v"(hi[1]));
  asm("v_cvt_pk_bf16_f32 %0, %1, %2" : "=v"(r.u[3]) : "v"(hi[2]), "v"(hi[3]));
  return r.v;
}

// ---------------------------------------------------------------------------
// bf16 MFMA GEMM: C[M,Nt] = A[M,K] @ B^T (+bias). B (Nt,K) bf16.
// AFP32=0: A bf16.  AFP32=1: A fp32, staged raw via global_load_lds and
// converted to bf16 at fragment-read time (v_cvt_pk_bf16_f32).
// swz=1: bijective XCD-chunked block swizzle. FUSE=1: fused a_src/a_dst dots.
// ---------------------------------------------------------------------------
template <int OBF, int FUSE, int AFP32>
__global__ __launch_bounds__(256) void gemm_bf16(
    const void* __restrict__ Ain, const u16* __restrict__ B,
    const float* __restrict__ bias, void* __restrict__ Cout,
    int M, int K, int Nt, int swz,
    const float* __restrict__ attS, const float* __restrict__ attD,
    float* __restrict__ asrc, float* __restrict__ adst)
{
  __shared__ __align__(16) char AsRaw[128 * 32 * 4];   // 16 KB (fp32) / 8 KB used (bf16)
  __shared__ u16 Bs[128][32];
  __shared__ float s_as[128], s_ad[128];
  float* AsF = (float*)AsRaw;
  u16 (*Asb)[32] = (u16(*)[32])AsRaw;
  const int tid  = threadIdx.x;
  const int wave = tid >> 6, lane = tid & 63;
  const int wr = (wave >> 1) * 64, wc = (wave & 1) * 64;
  int bx = blockIdx.x, by = blockIdx.y;
  if (swz) {
    const int gx = gridDim.x;
    const int nwg = gx * (int)gridDim.y;
    const int lin = by * gx + bx;
    const int q = nwg >> 3, r = nwg & 7;
    const int xcd = lin & 7, idx = lin >> 3;
    const int wg = (xcd < r ? xcd * (q + 1) : r * (q + 1) + (xcd - r) * q) + idx;
    bx = wg % gx; by = wg / gx;
  }
  const int bm = by * 128, bn = bx * 128;
  const int l15 = lane & 15, g = lane >> 4;

  if (FUSE && tid < 128) { s_as[tid] = 0.f; s_ad[tid] = 0.f; }

  // ---- staging source/dest setup ----
  const int sr = tid >> 2, sd = tid & 3;
  const int ss = sd ^ ((sr >> 1) & 3);
  // bf16-A path
  const u16* aS0 = 0; const u16* aS1 = 0; u16* lA0 = 0; u16* lA1 = 0;
  // fp32-A path (4 rounds, 8 slots of 4 floats per row, XOR slot swizzle)
  const float* aF[4]; float* lAF[4];
  if (AFP32) {
    const float* Af = (const float*)Ain;
    const int row0 = tid >> 3, sd8 = tid & 7;
    const int ss8 = sd8 ^ (row0 & 7);          // (row0 + p*32)&7 == row0&7
    #pragma unroll
    for (int p = 0; p < 4; ++p) {
      int row = row0 + p * 32;
      aF[p] = Af + (size_t)min(bm + row, M - 1) * K + ss8 * 4;
      lAF[p] = AsF + (size_t)(p * 256 + (tid & ~63)) * 4;
    }
  } else {
    const u16* Ab = (const u16*)Ain;
    aS0 = Ab + (size_t)min(bm + sr,      M - 1) * K + ss * 8;
    aS1 = Ab + (size_t)min(bm + 64 + sr, M - 1) * K + ss * 8;
    lA0 = (u16*)AsRaw + (size_t)(tid & ~63) * 8;
    lA1 = lA0 + 2048;
  }
  const u16* bS0 = B + (size_t)(bn + sr)      * K + ss * 8;
  const u16* bS1 = B + (size_t)(bn + 64 + sr) * K + ss * 8;
  u16* lB0 = &Bs[0][0] + (size_t)(tid & ~63) * 8;
  u16* lB1 = lB0 + 2048;

  f32x4 acc[4][4];
  #pragma unroll
  for (int m = 0; m < 4; ++m)
    #pragma unroll
    for (int n = 0; n < 4; ++n)
      #pragma unroll
      for (int j = 0; j < 4; ++j) acc[m][n][j] = 0.f;

  const int nK = K >> 5;
  for (int kt = 0; kt < nK; ++kt) {
    const int ko = kt * 32;
    if (AFP32) {
      #pragma unroll
      for (int p = 0; p < 4; ++p) gload16(aF[p] + ko, lAF[p]);
    } else {
      gload16(aS0 + ko, lA0);
      gload16(aS1 + ko, lA1);
    }
    gload16(bS0 + ko, lB0);
    gload16(bS1 + ko, lB1);
    __syncthreads();
    bf16x8 af[4], bfr[4];
    #pragma unroll
    for (int m = 0; m < 4; ++m) {
      int row = wr + m * 16 + l15;
      if (AFP32) {
        int s0 = (2 * g) ^ (row & 7), s1 = (2 * g + 1) ^ (row & 7);
        f32x4 lo = *(const f32x4*)&AsF[row * 32 + s0 * 4];
        f32x4 hi = *(const f32x4*)&AsF[row * 32 + s1 * 4];
        af[m] = cvt8(lo, hi);
      } else {
        af[m] = *(const bf16x8*)&Asb[row][(g ^ ((row >> 1) & 3)) * 8];
      }
      int rowb = wc + m * 16 + l15;
      bfr[m] = *(const bf16x8*)&Bs[rowb][(g ^ ((rowb >> 1) & 3)) * 8];
    }
    #pragma unroll
    for (int m = 0; m < 4; ++m)
      #pragma unroll
      for (int n = 0; n < 4; ++n)
        acc[m][n] = __builtin_amdgcn_mfma_f32_16x16x32_bf16(af[m], bfr[n], acc[m][n], 0, 0, 0);
    __syncthreads();
  }
  #pragma unroll
  for (int m = 0; m < 4; ++m) {
    int row0 = bm + wr + m * 16 + g * 4;
    #pragma unroll
    for (int n = 0; n < 4; ++n) {
      int col = bn + wc + n * 16 + l15;
      float bv = bias ? bias[col] : 0.f;
      #pragma unroll
      for (int j = 0; j < 4; ++j) {
        int row = row0 + j;
        if (row < M) {
          float v = acc[m][n][j] + bv;
          if (OBF) ((u16*)Cout)[(size_t)row * Nt + col] = f2b(v);
          else     ((float*)Cout)[(size_t)row * Nt + col] = v;
        }
      }
    }
  }
  if (FUSE) {
    float ps[4][4], pd[4][4];
    #pragma unroll
    for (int m = 0; m < 4; ++m)
      #pragma unroll
      for (int j = 0; j < 4; ++j) { ps[m][j] = 0.f; pd[m][j] = 0.f; }
    #pragma unroll
    for (int n = 0; n < 4; ++n) {
      int cl = wc + n * 16 + l15;
      float wsv = attS[bn + cl], wdv = attD[bn + cl];
      #pragma unroll
      for (int m = 0; m < 4; ++m)
        #pragma unroll
        for (int j = 0; j < 4; ++j) {
          ps[m][j] = fmaf(acc[m][n][j], wsv, ps[m][j]);
          pd[m][j] = fmaf(acc[m][n][j], wdv, pd[m][j]);
        }
    }
    #pragma unroll
    for (int m = 0; m < 4; ++m)
      #pragma unroll
      for (int j = 0; j < 4; ++j)
        #pragma unroll
        for (int msk = 8; msk >= 1; msk >>= 1) {
          ps[m][j] += __shfl_xor(ps[m][j], msk);
          pd[m][j] += __shfl_xor(pd[m][j], msk);
        }
    if (l15 == 0) {
      #pragma unroll
      for (int m = 0; m < 4; ++m)
        #pragma unroll
        for (int j = 0; j < 4; ++j) {
          atomicAdd(&s_as[wr + m * 16 + g * 4 + j], ps[m][j]);
          atomicAdd(&s_ad[wr + m * 16 + g * 4 + j], pd[m][j]);
        }
    }
    __syncthreads();
    if (tid < 128) {
      int row = bm + tid;
      if (row < M) {
        int h = bn >> 7;
        asrc[(size_t)row * 4 + h] = s_as[tid];
        adst[(size_t)row * 4 + h] = s_ad[tid];
      }
    }
  }
}

// ---------------------------------------------------------------------------
// merged small-weight converts: W_ih, W_hh, W_att_in, W_att_out (8 elems/thr)
// ---------------------------------------------------------------------------
__global__ void convert_weights(const float* __restrict__ w_ih, const float* __restrict__ w_hh,
                                const float* __restrict__ w_in, const float* __restrict__ w_out,
                                u16* __restrict__ wihb, u16* __restrict__ whhb,
                                u16* __restrict__ winb, u16* __restrict__ woutb)
{
  int i = blockIdx.x * 256 + threadIdx.x;   // 18432 threads
  const float* src; u16* dst; int base;
  if      (i < 6144)  { src = w_ih;  dst = wihb;  base = i; }
  else if (i < 12288) { src = w_hh;  dst = whhb;  base = i - 6144; }
  else if (i < 14336) { src = w_in;  dst = winb;  base = i - 12288; }
  else                { src = w_out; dst = woutb; base = i - 14336; }
  int o = base * 8;
  float4 v0 = *(const float4*)(src + o);
  float4 v1 = *(const float4*)(src + o + 4);
  bf16x8 ov;
  ov[0] = (short)f2b(v0.x); ov[1] = (short)f2b(v0.y);
  ov[2] = (short)f2b(v0.z); ov[3] = (short)f2b(v0.w);
  ov[4] = (short)f2b(v1.x); ov[5] = (short)f2b(v1.y);
  ov[6] = (short)f2b(v1.z); ov[7] = (short)f2b(v1.w);
  *(bf16x8*)(dst + o) = ov;
}

__global__ void conv_transpose_wgat(const float* __restrict__ src, u16* __restrict__ dst) {
  int idx = blockIdx.x * 256 + threadIdx.x;
  if (idx >= KC * F_INC) return;
  int n = idx >> 8, k = idx & 255;
  dst[(size_t)n * F_INC + k] = f2b(src[(size_t)k * KC + n]);
}

// ---------------------------------------------------------------------------
// Batched edge counting-sort (all T at once)
// ---------------------------------------------------------------------------
__global__ void count_kernel(const int* __restrict__ graph, int* __restrict__ counts) {
  int e = blockIdx.x * 256 + threadIdx.x;
  int t = blockIdx.y;
  if (e < N_EDGES) {
    int d = graph[(size_t)t * 2 * N_EDGES + N_EDGES + e];
    atomicAdd(&counts[t * N_NODES + d], 1);
  }
}

__global__ __launch_bounds__(1024) void scan_kernel(
    const int* __restrict__ counts, int* __restrict__ offs)
{
  const int t = blockIdx.x;
  const int tid = threadIdx.x, lane = tid & 63, w = tid >> 6;
  __shared__ int s_wt[16];
  int carry = 0;
  const int base_abs = t * SEG;
  for (int base = 0; base < N_NODES; base += 1024) {
    int i = base + tid;
    int v = (i < N_NODES) ? (counts[t * N_NODES + i] + 1) : 0;  // +1 self loop
    int x = v;
    #pragma unroll
    for (int d = 1; d < 64; d <<= 1) {
      int nvl = __shfl_up(x, d, 64);
      if (lane >= d) x += nvl;
    }
    if (lane == 63) s_wt[w] = x;
    __syncthreads();
    if (tid < 16) {
      int y = s_wt[tid];
      #pragma unroll
      for (int d = 1; d < 16; d <<= 1) {
        int nvl = __shfl_up(y, d, 64);
        if (tid >= d) y += nvl;
      }
      s_wt[tid] = y;
    }
    __syncthreads();
    int wbase = (w > 0) ? s_wt[w - 1] : 0;
    int total = s_wt[15];
    if (i < N_NODES) offs[t * (N_NODES + 1) + i] = base_abs + carry + wbase + x - v;
    carry += total;
    __syncthreads();
  }
  if (tid == 0) offs[t * (N_NODES + 1) + N_NODES] = base_abs + carry;
}

__global__ void scatter_kernel(const int* __restrict__ graph, const int* __restrict__ offs,
                               int* __restrict__ cursor, int* __restrict__ ssrc)
{
  int i = blockIdx.x * 256 + threadIdx.x;
  int t = blockIdx.y;
  if (i >= SEG) return;
  int s, d;
  if (i < N_EDGES) {
    s = graph[(size_t)t * 2 * N_EDGES + i];
    d = graph[(size_t)t * 2 * N_EDGES + N_EDGES + i];
  } else {
    s = d = i - N_EDGES;
  }
  int pos = offs[t * (N_NODES + 1) + d] + atomicAdd(&cursor[t * N_NODES + d], 1);
  ssrc[pos] = s;
}

// ---------------------------------------------------------------------------
// Batched aggregate (unchanged from round 6): head-interleaved online softmax
// + branch-free padded 8-wide gather. Zero LDS.
// ---------------------------------------------------------------------------
__global__ __launch_bounds__(256) void aggregate_kernel(
    const u16* __restrict__ xw, const float* __restrict__ a_src,
    const float* __restrict__ a_dst, const float* __restrict__ b_gat,
    const int* __restrict__ offs, const int* __restrict__ ssrc,
    u16* __restrict__ yout)
{
  const int wv = threadIdx.x >> 6, lane = threadIdx.x & 63;
  const int nd = blockIdx.x * 4 + wv;
  const int t  = blockIdx.y;
  const int ob = t * (N_NODES + 1) + nd;
  const int beg = offs[ob], end = offs[ob + 1];
  const size_t rowbase = (size_t)t * N_NODES;
  const int he   = lane & 3;
  const int eidx = lane >> 2;
  const int hl   = lane >> 4;
  const float advh = a_dst[(rowbase + nd) * 4 + he];

  float m = -INFINITY, ssum = 0.f;
  float acc[8] = {0.f,0.f,0.f,0.f,0.f,0.f,0.f,0.f};

#define FMA8(W, X)                                                        \
    { float _w = (W);                                                     \
      acc[0] = fmaf(_w, __uint_as_float((unsigned)(X).x << 16), acc[0]);  \
      acc[1] = fmaf(_w, __uint_as_float((unsigned)(X).x & 0xffff0000u), acc[1]); \
      acc[2] = fmaf(_w, __uint_as_float((unsigned)(X).y << 16), acc[2]);  \
      acc[3] = fmaf(_w, __uint_as_float((unsigned)(X).y & 0xffff0000u), acc[3]); \
      acc[4] = fmaf(_w, __uint_as_float((unsigned)(X).z << 16), acc[4]);  \
      acc[5] = fmaf(_w, __uint_as_float((unsigned)(X).z & 0xffff0000u), acc[5]); \
      acc[6] = fmaf(_w, __uint_as_float((unsigned)(X).w << 16), acc[6]);  \
      acc[7] = fmaf(_w, __uint_as_float((unsigned)(X).w & 0xffff0000u), acc[7]); }
#define LDE(SVAR) (*(const int4*)&xw[(rowbase + (SVAR)) * KC + lane * 8])

  for (int base = beg; base < end; base += 16) {
    const int cnt = min(16, end - base);
    const int e = base + eidx;
    const int sidx = (e < end) ? ssrc[e] : ssrc[base];
    const float av = a_src[(rowbase + sidx) * 4 + he];
    const float a = (eidx < cnt) ? leakyf(av + advh) : -INFINITY;
    float cm = a;
    cm = fmaxf(cm, __shfl_xor(cm, 4));
    cm = fmaxf(cm, __shfl_xor(cm, 8));
    cm = fmaxf(cm, __shfl_xor(cm, 16));
    cm = fmaxf(cm, __shfl_xor(cm, 32));
    const float nm = fmaxf(m, cm);
    const float sc = expf(m - nm);
    const float w = expf(a - nm);
    float ts = w;
    ts += __shfl_xor(ts, 4);
    ts += __shfl_xor(ts, 8);
    ts += __shfl_xor(ts, 16);
    ts += __shfl_xor(ts, 32);
    ssum = ssum * sc + ts;
    m = nm;
    const float schl = __shfl(sc, hl);
    #pragma unroll
    for (int k = 0; k < 8; ++k) acc[k] *= schl;

    const int cpad = (cnt + 3) & ~3;
    int b4 = 0;
    for (; b4 + 8 <= cpad; b4 += 8) {
      const int s0 = __shfl(sidx, (b4 + 0) << 2);
      const int s1 = __shfl(sidx, (b4 + 1) << 2);
      const int s2 = __shfl(sidx, (b4 + 2) << 2);
      const int s3 = __shfl(sidx, (b4 + 3) << 2);
      const int s4 = __shfl(sidx, (b4 + 4) << 2);
      const int s5 = __shfl(sidx, (b4 + 5) << 2);
      const int s6 = __shfl(sidx, (b4 + 6) << 2);
      const int s7 = __shfl(sidx, (b4 + 7) << 2);
      const int4 x0 = LDE(s0); const int4 x1 = LDE(s1);
      const int4 x2 = LDE(s2); const int4 x3 = LDE(s3);
      const int4 x4 = LDE(s4); const int4 x5 = LDE(s5);
      const int4 x6 = LDE(s6); const int4 x7 = LDE(s7);
      const float w0 = __shfl(w, ((b4 + 0) << 2) + hl);
      const float w1 = __shfl(w, ((b4 + 1) << 2) + hl);
      const float w2 = __shfl(w, ((b4 + 2) << 2) + hl);
      const float w3 = __shfl(w, ((b4 + 3) << 2) + hl);
      const float w4 = __shfl(w, ((b4 + 4) << 2) + hl);
      const float w5 = __shfl(w, ((b4 + 5) << 2) + hl);
      const float w6 = __shfl(w, ((b4 + 6) << 2) + hl);
      const float w7 = __shfl(w, ((b4 + 7) << 2) + hl);
      FMA8(w0, x0); FMA8(w1, x1); FMA8(w2, x2); FMA8(w3, x3);
      FMA8(w4, x4); FMA8(w5, x5); FMA8(w6, x6); FMA8(w7, x7);
    }
    if (b4 < cpad) {
      const int s0 = __shfl(sidx, (b4 + 0) << 2);
      const int s1 = __shfl(sidx, (b4 + 1) << 2);
      const int s2 = __shfl(sidx, (b4 + 2) << 2);
      const int s3 = __shfl(sidx, (b4 + 3) << 2);
      const int4 x0 = LDE(s0); const int4 x1 = LDE(s1);
      const int4 x2 = LDE(s2); const int4 x3 = LDE(s3);
      const float w0 = __shfl(w, ((b4 + 0) << 2) + hl);
      const float w1 = __shfl(w, ((b4 + 1) << 2) + hl);
      const float w2 = __shfl(w, ((b4 + 2) << 2) + hl);
      const float w3 = __shfl(w, ((b4 + 3) << 2) + hl);
      FMA8(w0, x0); FMA8(w1, x1); FMA8(w2, x2); FMA8(w3, x3);
    }
  }
#undef LDE
#undef FMA8

  const float sh = __shfl(ssum, hl);
  const float inv = 1.f / (sh + 1e-16f);
  #pragma unroll
  for (int k = 0; k < 8; ++k) {
    acc[k] *= inv;
    acc[k] += __shfl_xor(acc[k], 16);
    acc[k] += __shfl_xor(acc[k], 32);
  }
  if (lane < 16) {
    bf16x8 ov;
    #pragma unroll
    for (int k = 0; k < 8; ++k) {
      float v = acc[k] * 0.25f + b_gat[lane * 8 + k];
      ov[k] = (short)f2b(leakyf(v));
    }
    *(bf16x8*)&yout[(rowbase + nd) * GHD + lane * 8] = ov;
  }
}

// ---------------------------------------------------------------------------
// Fused full GRU recurrence: ONE kernel, 625 blocks x 32 rows, 8 steps.
// h carried fp32 in registers (hp) + bf16 in swizzled LDS tile hA that feeds
// next step's MFMA A-fragments. W_hh staged per-kt via global_load_lds
// (L2-hot). gh staged through LDS (reuses Bs region). ctx[t] written bf16.
// Rows are independent across the recurrence -> no inter-block comm.
// ---------------------------------------------------------------------------
__global__ __launch_bounds__(256) void gru_seq(
    const u16* __restrict__ Whh, const float* __restrict__ b_hh,
    const u16* __restrict__ giall, u16* __restrict__ ctx)
{
  __shared__ u16 hA[32][128];       // 8 KB: h bf16, slot-swizzled (slot^row&7)
  __shared__ u16 reg2[12288];       // 24 KB: Bs (384x32) during MFMA, gh after
  u16 (*Bs)[32] = (u16(*)[32])reg2;
  const int tid = threadIdx.x, lane = tid & 63, wv = tid >> 6;
  const int l15 = lane & 15, g = lane >> 4;
  const int bm = blockIdx.x * 32;   // 20000 = 625*32, no tail

  // W_hh staging (same scheme as proven gru_fused)
  const int sr = tid >> 2, sd = tid & 3;
  const int ssb = sd ^ ((sr >> 1) & 3);
  const u16* bS[6]; u16* lB[6];
  #pragma unroll
  for (int p = 0; p < 6; ++p) {
    bS[p] = Whh + (size_t)(sr + p * 64) * GHD + ssb * 8;
    lB[p] = reg2 + (size_t)(p * 256 + (tid & ~63)) * 8;
  }
  // hoisted b_hh for gh staging (c depends only on wv,n,l15)
  float bbv[6];
  #pragma unroll
  for (int n = 0; n < 6; ++n) bbv[n] = b_hh[wv * 96 + n * 16 + l15];

  // combine mapping: row cr, channels {cg..cg+7} u {64+cg..64+cg+7}
  const int cr = tid >> 3;
  const int cg = (tid & 7) * 8;
  const int grow = bm + cr;
  const size_t gb = (size_t)grow * G3;
  const size_t cb = (size_t)grow * GHD;
  float hp[2][8];

  // ---- t = 0: h = (1-z)*tanh(i_n + r*b_hh_n), gh == b_hh ----
  #pragma unroll
  for (int q = 0; q < 2; ++q) {
    const int c0 = cg + q * 64;
    bf16x8 ir8 = *(const bf16x8*)&giall[gb + c0];
    bf16x8 iz8 = *(const bf16x8*)&giall[gb + 128 + c0];
    bf16x8 in8 = *(const bf16x8*)&giall[gb + 256 + c0];
    float4 br0 = *(const float4*)&b_hh[c0];       float4 br1 = *(const float4*)&b_hh[c0 + 4];
    float4 bz0 = *(const float4*)&b_hh[128 + c0]; float4 bz1 = *(const float4*)&b_hh[128 + c0 + 4];
    float4 bn0 = *(const float4*)&b_hh[256 + c0]; float4 bn1 = *(const float4*)&b_hh[256 + c0 + 4];
    float bhr[8] = {br0.x, br0.y, br0.z, br0.w, br1.x, br1.y, br1.z, br1.w};
    float bhz[8] = {bz0.x, bz0.y, bz0.z, bz0.w, bz1.x, bz1.y, bz1.z, bz1.w};
    float bhn[8] = {bn0.x, bn0.y, bn0.z, bn0.w, bn1.x, bn1.y, bn1.z, bn1.w};
    bf16x8 hv;
    #pragma unroll
    for (int k = 0; k < 8; ++k) {
      float rr = sigf(b2f((u16)ir8[k]) + bhr[k]);
      float zz = sigf(b2f((u16)iz8[k]) + bhz[k]);
      float nn = tanhf(b2f((u16)in8[k]) + rr * bhn[k]);
      float h = (1.f - zz) * nn;
      hp[q][k] = h;
      hv[k] = (short)f2b(h);
    }
    const int sl = (c0 >> 3) ^ (cr & 7);
    *(bf16x8*)&hA[cr][sl * 8] = hv;
    *(bf16x8*)&ctx[cb + c0] = hv;
  }
  __syncthreads();

  // ---- t = 1..7 ----
  for (int t = 1; t < T_STEPS; ++t) {
    const u16* gi_t = giall + (size_t)t * N_NODES * G3;
    u16* ctx_t = ctx + (size_t)t * N_NODES * GHD;
    f32x4 acc[2][6];
    #pragma unroll
    for (int m = 0; m < 2; ++m)
      #pragma unroll
      for (int n = 0; n < 6; ++n)
        #pragma unroll
        for (int j = 0; j < 4; ++j) acc[m][n][j] = 0.f;

    #pragma unroll
    for (int kt = 0; kt < 4; ++kt) {
      const int ko = kt * 32;
      #pragma unroll
      for (int p = 0; p < 6; ++p) gload16(bS[p] + ko, lB[p]);
      __syncthreads();
      bf16x8 af[2], bfr[6];
      #pragma unroll
      for (int m = 0; m < 2; ++m) {
        int row = m * 16 + l15;
        int sl = (kt * 4 + g) ^ (row & 7);
        af[m] = *(const bf16x8*)&hA[row][sl * 8];
      }
      #pragma unroll
      for (int n = 0; n < 6; ++n) {
        int rowb = wv * 96 + n * 16 + l15;
        bfr[n] = *(const bf16x8*)&Bs[rowb][(g ^ ((rowb >> 1) & 3)) * 8];
      }
      #pragma unroll
      for (int m = 0; m < 2; ++m)
        #pragma unroll
        for (int n = 0; n < 6; ++n)
          acc[m][n] = __builtin_amdgcn_mfma_f32_16x16x32_bf16(af[m], bfr[n], acc[m][n], 0, 0, 0);
      __syncthreads();
    }
    // stage gh (+b_hh) into reg2 (clobbers Bs; all reads done)
    #pragma unroll
    for (int m = 0; m < 2; ++m)
      #pragma unroll
      for (int n = 0; n < 6; ++n) {
        int c = wv * 96 + n * 16 + l15;
        #pragma unroll
        for (int j = 0; j < 4; ++j) {
          int r = m * 16 + g * 4 + j;
          reg2[r * 384 + (((c >> 3) ^ (r & 7)) << 3) + (c & 7)] = f2b(acc[m][n][j] + bbv[n]);
        }
      }
    __syncthreads();
    // combine (reads reg2, writes hA + ctx; hp carries fp32 state)
    #pragma unroll
    for (int q = 0; q < 2; ++q) {
      const int c0 = cg + q * 64;
      const int sl0 = ((c0 >> 3) ^ (cr & 7));
      const int sl1 = (((128 + c0) >> 3) ^ (cr & 7));
      const int sl2 = (((256 + c0) >> 3) ^ (cr & 7));
      bf16x8 hr8 = *(bf16x8*)&reg2[cr * 384 + sl0 * 8];
      bf16x8 hz8 = *(bf16x8*)&reg2[cr * 384 + sl1 * 8];
      bf16x8 hn8 = *(bf16x8*)&reg2[cr * 384 + sl2 * 8];
      bf16x8 ir8 = *(const bf16x8*)&gi_t[gb + c0];
      bf16x8 iz8 = *(const bf16x8*)&gi_t[gb + 128 + c0];
      bf16x8 in8 = *(const bf16x8*)&gi_t[gb + 256 + c0];
      bf16x8 hv;
      #pragma unroll
      for (int k = 0; k < 8; ++k) {
        float rr = sigf(b2f((u16)ir8[k]) + b2f((u16)hr8[k]));
        float zz = sigf(b2f((u16)iz8[k]) + b2f((u16)hz8[k]));
        float nn = tanhf(b2f((u16)in8[k]) + rr * b2f((u16)hn8[k]));
        float h = (1.f - zz) * nn + zz * hp[q][k];
        hp[q][k] = h;
        hv[k] = (short)f2b(h);
      }
      const int slh = (c0 >> 3) ^ (cr & 7);
      *(bf16x8*)&hA[cr][slh * 8] = hv;
      *(bf16x8*)&ctx_t[cb + c0] = hv;
    }
    __syncthreads();   // reg2/hA safe for next step
  }
}

// ---------------------------------------------------------------------------
// Temporal attention middle: scores + softmax + mix. One wave / node.
// ---------------------------------------------------------------------------
__global__ __launch_bounds__(256) void attn_mid(
    const u16* __restrict__ ctx, const float* __restrict__ q,
    u16* __restrict__ comb)
{
  const int node = blockIdx.x * 4 + (threadIdx.x >> 6);
  const int lane = threadIdx.x & 63;
  if (node >= N_NODES) return;
  const float q0 = q[(size_t)node * GHD + lane];
  const float q1 = q[(size_t)node * GHD + 64 + lane];
  float c0[T_STEPS], c1[T_STEPS], w[T_STEPS];
  float mx = -1e30f;
  #pragma unroll
  for (int t = 0; t < T_STEPS; ++t) {
    const u16* cr = ctx + ((size_t)t * N_NODES + node) * GHD;
    c0[t] = b2f(cr[lane]); c1[t] = b2f(cr[64 + lane]);
    float p = q0 * c0[t] + q1 * c1[t];
    #pragma unroll
    for (int m = 32; m >= 1; m >>= 1) p += __shfl_xor(p, m);
    w[t] = p;
    mx = fmaxf(mx, p);
  }
  float s = 0.f;
  #pragma unroll
  for (int t = 0; t < T_STEPS; ++t) { w[t] = expf(w[t] - mx); s += w[t]; }
  const float inv = 1.f / s;
  float m0 = 0.f, m1 = 0.f;
  #pragma unroll
  for (int t = 0; t < T_STEPS; ++t) { m0 = fmaf(w[t], c0[t], m0); m1 = fmaf(w[t], c1[t], m1); }
  m0 *= inv; m1 *= inv;
  u16* cb = comb + (size_t)node * 2 * GHD;
  cb[lane]       = f2b(m0);
  cb[64 + lane]  = f2b(m1);
  cb[128 + lane] = f2b(q0);
  cb[192 + lane] = f2b(q1);
}

// ---------------------------------------------------------------------------
// tanh + leaky + classifier + log_softmax. One wave / node.
// ---------------------------------------------------------------------------
__global__ __launch_bounds__(256) void logits_kernel(
    const u16* __restrict__ ao, const float* __restrict__ W_cls,
    const float* __restrict__ b_cls, float* __restrict__ out)
{
  const int node = blockIdx.x * 4 + (threadIdx.x >> 6);
  const int lane = threadIdx.x & 63;
  if (node >= N_NODES) return;
  float o0 = leakyf(tanhf(b2f(ao[(size_t)node * GHD + lane])));
  float o1 = leakyf(tanhf(b2f(ao[(size_t)node * GHD + 64 + lane])));
  float p0 = o0 * W_cls[lane] + o1 * W_cls[64 + lane];
  float p1 = o0 * W_cls[128 + lane] + o1 * W_cls[192 + lane];
  #pragma unroll
  for (int m = 32; m >= 1; m >>= 1) { p0 += __shfl_xor(p0, m); p1 += __shfl_xor(p1, m); }
  if (lane == 0) {
    float l0 = p0 + b_cls[0];
    float l1 = p1 + b_cls[1];
    float mx = fmaxf(l0, l1);
    float lse = mx + logf(expf(l0 - mx) + expf(l1 - mx));
    out[(size_t)node * 2 + 0] = l0 - lse;
    out[(size_t)node * 2 + 1] = l1 - lse;
  }
}

// ---------------------------------------------------------------------------
extern "C" void kernel_launch(void* const* d_in, const int* in_sizes, int n_in,
                              void* d_out, int out_size, void* d_ws, size_t ws_size,
                              hipStream_t stream)
{
  const int*   graph     = (const int*)  d_in[0];
  const float* fts       = (const float*)d_in[1];
  const float* W_gat     = (const float*)d_in[3];
  const float* att_src   = (const float*)d_in[4];
  const float* att_dst   = (const float*)d_in[5];
  const float* b_gat     = (const float*)d_in[6];
  const float* W_ih      = (const float*)d_in[7];
  const float* W_hh      = (const float*)d_in[8];
  const float* b_ih      = (const float*)d_in[9];
  const float* b_hh      = (const float*)d_in[10];
  const float* W_att_in  = (const float*)d_in[11];
  const float* W_att_out = (const float*)d_in[12];
  const float* W_cls     = (const float*)d_in[13];
  const float* b_cls     = (const float*)d_in[14];
  float* out = (float*)d_out;

  char* ws = (char*)d_ws;
  size_t off = 0;
  auto alloc = [&](size_t bytes) {
    void* p = ws + off;
    off = (off + bytes + 255) & ~(size_t)255;
    return p;
  };
  const size_t NT = (size_t)T_STEPS * N_NODES;      // 160000 rows
  u16*   wgatT = (u16*)alloc((size_t)KC * F_INC * 2);
  u16*   wihb  = (u16*)alloc((size_t)G3 * GHD * 2);
  u16*   whhb  = (u16*)alloc((size_t)G3 * GHD * 2);
  u16*   winb  = (u16*)alloc((size_t)GHD * GHD * 2);
  u16*   woutb = (u16*)alloc((size_t)GHD * 2 * GHD * 2);
  u16*   xw    = (u16*)alloc(NT * KC * 2);          // 164 MB
  float* asrc  = (float*)alloc(NT * 4 * 4);
  float* adst  = (float*)alloc(NT * 4 * 4);
  u16*   yall  = (u16*)alloc(NT * GHD * 2);         // 41 MB
  u16*   giall = (u16*)alloc(NT * G3 * 2);          // 123 MB
  u16*   ctx   = (u16*)alloc(NT * GHD * 2);         // 41 MB (bf16 h record)
  float* qf    = (float*)alloc((size_t)N_NODES * GHD * 4);
  u16*   comb  = (u16*)alloc((size_t)N_NODES * 2 * GHD * 2);
  u16*   aob   = (u16*)alloc((size_t)N_NODES * GHD * 2);
  int* counts  = (int*)alloc((size_t)2 * T_STEPS * N_NODES * 4); // counts + cursor
  int* cursor  = counts + T_STEPS * N_NODES;
  int* offs    = (int*)alloc((size_t)T_STEPS * (N_NODES + 1) * 4);
  int* ssrc    = (int*)alloc((size_t)T_STEPS * SEG * 4);

  // weight converts
  conv_transpose_wgat<<<dim3((KC * F_INC + 255) / 256), 256, 0, stream>>>(W_gat, wgatT);
  convert_weights<<<dim3(72), 256, 0, stream>>>(W_ih, W_hh, W_att_in, W_att_out,
                                                wihb, whhb, winb, woutb);

  // batched edge sort
  hipMemsetAsync(counts, 0, (size_t)2 * T_STEPS * N_NODES * 4, stream);
  count_kernel<<<dim3(N_EDGES / 256, T_STEPS), 256, 0, stream>>>(graph, counts);
  scan_kernel<<<dim3(T_STEPS), 1024, 0, stream>>>(counts, offs);
  scatter_kernel<<<dim3((SEG + 255) / 256, T_STEPS), 256, 0, stream>>>(graph, offs, cursor, ssrc);

  // xw = fts(fp32) @ W_gat^T for ALL t (convert fused into A staging)
  gemm_bf16<1, 1, 1><<<dim3(KC / 128, (int)(NT / 128)), 256, 0, stream>>>(
      fts, wgatT, nullptr, xw, (int)NT, F_INC, KC, 1, att_src, att_dst, asrc, adst);

  // batched aggregate -> y for ALL t
  aggregate_kernel<<<dim3(N_NODES / 4, T_STEPS), 256, 0, stream>>>(
      xw, asrc, adst, b_gat, offs, ssrc, yall);

  // gi = y @ W_ih^T + b_ih for ALL t
  gemm_bf16<1, 0, 0><<<dim3(G3 / 128, (int)(NT / 128)), 256, 0, stream>>>(
      yall, wihb, b_ih, giall, (int)NT, GHD, G3, 1, nullptr, nullptr, nullptr, nullptr);

  // fused full GRU recurrence (single kernel)
  gru_seq<<<dim3(N_NODES / 32), 256, 0, stream>>>(whhb, b_hh, giall, ctx);

  // temporal attention tail
  gemm_bf16<0, 0, 0><<<dim3(1, (N_NODES + 127) / 128), 256, 0, stream>>>(
      ctx + (size_t)(T_STEPS - 1) * N_NODES * GHD, winb, nullptr, qf,
      N_NODES, GHD, GHD, 0, nullptr, nullptr, nullptr, nullptr);
  attn_mid<<<dim3(N_NODES / 4), 256, 0, stream>>>(ctx, qf, comb);
  gemm_bf16<1, 0, 0><<<dim3(1, (N_NODES + 127) / 128), 256, 0, stream>>>(
      comb, woutb, nullptr, aob, N_NODES, 2 * GHD, GHD, 0, nullptr, nullptr, nullptr, nullptr);
  logits_kernel<<<dim3(N_NODES / 4), 256, 0, stream>>>(aob, W_cls, b_cls, out);
}